// Round 14
// baseline (1218.276 us; speedup 1.0000x reference)
//
#include <hip/hip_runtime.h>
#include <stdint.h>

#define B_    256
#define T_    77
#define E_    1280
#define H_    20
#define T2_   154
#define MTOK  19712   // B_*T_
#define MTOK2 39424   // B_*T2_

typedef float f32x4 __attribute__((ext_vector_type(4)));
typedef short bf16x8 __attribute__((ext_vector_type(8)));

__device__ inline float bf2f(short s) {
    return __uint_as_float(((unsigned)(unsigned short)s) << 16);
}
__device__ inline short f2bf(float f) {
    unsigned u = __float_as_uint(f);
    u += 0x7fff + ((u >> 16) & 1);   // RNE
    return (short)(u >> 16);
}
__device__ inline float gelu_tanh(float x) {   // jax.nn.gelu approximate=True
    float x3 = x * x * x;
    return 0.5f * x * (1.0f + tanhf(0.7978845608028654f * (x + 0.044715f * x3)));
}

// ---------------- fp32 -> bf16 cast ----------------
__global__ void cast_f32_bf16(const float* __restrict__ in, short* __restrict__ out, int n4) {
    int i = blockIdx.x * blockDim.x + threadIdx.x;
    int stride = gridDim.x * blockDim.x;
    for (; i < n4; i += stride) {
        float4 v = reinterpret_cast<const float4*>(in)[i];
        short4 o;
        o.x = f2bf(v.x); o.y = f2bf(v.y); o.z = f2bf(v.z); o.w = f2bf(v.w);
        reinterpret_cast<short4*>(out)[i] = o;
    }
}

// ---------------- merged 8-weight cast ----------------
__global__ void cast8_f32_bf16(const float* __restrict__ s0, const float* __restrict__ s1,
                               const float* __restrict__ s2, const float* __restrict__ s3,
                               const float* __restrict__ s4, const float* __restrict__ s5,
                               const float* __restrict__ s6, const float* __restrict__ s7,
                               short* __restrict__ out) {
    const int per = E_ * E_ / 4;
    int i = blockIdx.x * blockDim.x + threadIdx.x;
    int stride = gridDim.x * blockDim.x;
    for (; i < 8 * per; i += stride) {
        int w = i / per, j = i - w * per;
        const float* src = w == 0 ? s0 : w == 1 ? s1 : w == 2 ? s2 : w == 3 ? s3
                         : w == 4 ? s4 : w == 5 ? s5 : w == 6 ? s6 : s7;
        float4 v = reinterpret_cast<const float4*>(src)[j];
        short4 o;
        o.x = f2bf(v.x); o.y = f2bf(v.y); o.z = f2bf(v.z); o.w = f2bf(v.w);
        reinterpret_cast<short4*>(out)[i] = o;
    }
}

// ---------------- pad token-mix weight ----------------
__global__ void pad_weight(const float* __restrict__ W, short* __restrict__ Wp,
                           int rows, int cols, int KP) {
    int i = blockIdx.x * 256 + threadIdx.x;
    if (i >= 80 * KP) return;
    int t = i / KP, s = i - t * KP;
    Wp[i] = (t < rows && s < cols) ? f2bf(W[t * cols + s]) : (short)0;
}

// ================= 4-phase 256x256 GEMM, reg-cached fragments =================
// R13 failed at 20% MfmaUtil: 12 ds_read_b128/wave/phase = 96/CU ~ 1150 cy >>
// 516 cy MFMA/SIMD -> LDS-issue-bound in barrier lockstep. This version cuts
// reads to the 24/K-step minimum, balanced {4,4,8,8} per phase:
//   quadrants (0,0)->(0,1)->(1,1)->(1,0); Bf0/Bf1 cached across the K-step
//   (B0 reused p3, B1 reused p2); A frags double-buffered AfA/AfB with A0(t+1)
//   PRE-READ at p3(t) from the other-parity buffer (landed per ledger).
// Per-wave vmcnt ledger (2 loads per STAGE; issue A0,B0,B1,A1 per tile):
//   prologue: issue 4 -> 8 out; vmcnt(6) drains A0; read A0->AfA.
//   p0: out[B0,B1,A1]=6, vmcnt(4) drains B0; issue A0' -> 6; read B0.
//   p1: vmcnt(4) drains B1; issue B0' -> 6; read B1.
//   p2: vmcnt(4) drains A1; issue B1' -> 6; read A1->AfB.
//   p3: vmcnt(4) drains A0'; issue A1' -> 6; read A0'(nxt parity)->AfA.
// Never drains below 4 in the loop. WAR: every slot overwrite-issue is >=5
// phase-barriers after its last ds_read. Epilogue drains 4->2->0.
template<int NSEG, int EPI>   // EPI 0: (+bias)*scl(seg0) -> bf16 ; 2: gelu -> bf16
__global__ __launch_bounds__(512, 2)
void qgemm(const short* __restrict__ A, const short* __restrict__ W,
           const float* __restrict__ b0, const float* __restrict__ b1,
           const float* __restrict__ b2,
           short* __restrict__ o0, short* __restrict__ o1, short* __restrict__ o2,
           float s0) {
    const int K = E_;
    const int NT = K / 64;            // 20
    __shared__ short As[2 * 2 * 8192];    // [parity][half][128*64]
    __shared__ short Bs[2 * 2 * 8192];
    const int tid = threadIdx.x;
    const int wave = tid >> 6, lane = tid & 63;
    const int wr = wave >> 2, wc = wave & 3;

    // T1 bijective XCD swizzle; seg-major, bn-fast (5 N-tiles of 256 per seg)
    const int nwg = gridDim.x;
    const int qq = nwg >> 3, rr = nwg & 7;
    const int x = blockIdx.x & 7, ii = blockIdx.x >> 3;
    const int L = (x < rr ? x * (qq + 1) : rr * (qq + 1) + (x - rr) * qq) + ii;
    const int PB = nwg / NSEG;
    const int seg = L / PB;
    const int rem = L - seg * PB;
    const int bm = rem / 5, bnl = rem % 5;

    const long arow0 = (long)bm * 256;
    const long brow0 = (long)seg * E_ + bnl * 256;

    const int rsub = lane >> 3;
    const int colswz = (((lane & 7) ^ rsub) & 7) * 8;
    const int swz = (lane & 7) << 3;

    f32x4 acc[8][4] = {};
    bf16x8 AfA[4][2], AfB[4][2], Bf0[2][2], Bf1[2][2];

    auto STAGE_A = [&](int par, int half, int kt) {
#pragma unroll
        for (int i = 0; i < 2; ++i) {
            int chunk = i * 8 + wave;
            int row = chunk * 8 + rsub;
            const short* ga = A + (arow0 + half * 128 + row) * K + kt * 64 + colswz;
            __builtin_amdgcn_global_load_lds(
                (const __attribute__((address_space(1))) unsigned int*)ga,
                (__attribute__((address_space(3))) unsigned int*)
                    &As[par * 16384 + half * 8192 + chunk * 512], 16, 0, 0);
        }
    };
    auto STAGE_B = [&](int par, int half, int kt) {
#pragma unroll
        for (int i = 0; i < 2; ++i) {
            int chunk = i * 8 + wave;
            int row = chunk * 8 + rsub;
            const short* gb = W + (brow0 + half * 128 + row) * K + kt * 64 + colswz;
            __builtin_amdgcn_global_load_lds(
                (const __attribute__((address_space(1))) unsigned int*)gb,
                (__attribute__((address_space(3))) unsigned int*)
                    &Bs[par * 16384 + half * 8192 + chunk * 512], 16, 0, 0);
        }
    };
    auto LDA = [&](bf16x8 (&dst)[4][2], int par, int hm) {
#pragma unroll
        for (int mi = 0; mi < 4; ++mi)
#pragma unroll
            for (int kk = 0; kk < 2; ++kk)
                dst[mi][kk] = *reinterpret_cast<const bf16x8*>(
                    &As[par * 16384 + hm * 8192 +
                        (((wr * 64 + mi * 16 + (lane & 15)) * 64 + kk * 32 +
                          (lane >> 4) * 8) ^ swz)]);
    };
    auto LDB = [&](bf16x8 (&dst)[2][2], int par, int hn) {
#pragma unroll
        for (int nj = 0; nj < 2; ++nj)
#pragma unroll
            for (int kk = 0; kk < 2; ++kk)
                dst[nj][kk] = *reinterpret_cast<const bf16x8*>(
                    &Bs[par * 16384 + hn * 8192 +
                        (((wc * 32 + nj * 16 + (lane & 15)) * 64 + kk * 32 +
                          (lane >> 4) * 8) ^ swz)]);
    };
    auto MFMA16 = [&](int hm, bf16x8 (&Af)[4][2], bf16x8 (&Bf)[2][2], int hn) {
        __builtin_amdgcn_s_setprio(1);
#pragma unroll
        for (int mi = 0; mi < 4; ++mi)
#pragma unroll
            for (int nj = 0; nj < 2; ++nj)
#pragma unroll
                for (int kk = 0; kk < 2; ++kk)
                    acc[hm * 4 + mi][hn * 2 + nj] =
                        __builtin_amdgcn_mfma_f32_16x16x32_bf16(
                            Af[mi][kk], Bf[nj][kk], acc[hm * 4 + mi][hn * 2 + nj],
                            0, 0, 0);
        __builtin_amdgcn_s_setprio(0);
    };

    // prologue: tile 0, issue order A0,B0,B1,A1; pre-read A0 -> AfA
    STAGE_A(0, 0, 0); STAGE_B(0, 0, 0); STAGE_B(0, 1, 0); STAGE_A(0, 1, 0);
    asm volatile("s_waitcnt vmcnt(6)" ::: "memory");
    __builtin_amdgcn_s_barrier(); __builtin_amdgcn_sched_barrier(0);
    LDA(AfA, 0, 0);

    for (int t = 0; t < NT - 1; ++t) {
        const int par = t & 1, nxt = par ^ 1;
        // p0: quad (0,0) — needs B0(t)
        asm volatile("s_waitcnt vmcnt(4)" ::: "memory");
        __builtin_amdgcn_s_barrier(); __builtin_amdgcn_sched_barrier(0);
        LDB(Bf0, par, 0);
        STAGE_A(nxt, 0, t + 1);
        MFMA16(0, AfA, Bf0, 0);
        // p1: quad (0,1) — needs B1(t)
        asm volatile("s_waitcnt vmcnt(4)" ::: "memory");
        __builtin_amdgcn_s_barrier(); __builtin_amdgcn_sched_barrier(0);
        LDB(Bf1, par, 1);
        STAGE_B(nxt, 0, t + 1);
        MFMA16(0, AfA, Bf1, 1);
        // p2: quad (1,1) — needs A1(t)
        asm volatile("s_waitcnt vmcnt(4)" ::: "memory");
        __builtin_amdgcn_s_barrier(); __builtin_amdgcn_sched_barrier(0);
        LDA(AfB, par, 1);
        STAGE_B(nxt, 1, t + 1);
        MFMA16(1, AfB, Bf1, 1);
        // p3: quad (1,0) — pre-reads A0(t+1) from nxt parity
        asm volatile("s_waitcnt vmcnt(4)" ::: "memory");
        __builtin_amdgcn_s_barrier(); __builtin_amdgcn_sched_barrier(0);
        LDA(AfA, nxt, 0);
        STAGE_A(nxt, 1, t + 1);
        MFMA16(1, AfB, Bf0, 0);
    }
    {   // last tile: drain 4 -> 2 -> 0, no issues
        const int par = (NT - 1) & 1;
        asm volatile("s_waitcnt vmcnt(4)" ::: "memory");
        __builtin_amdgcn_s_barrier(); __builtin_amdgcn_sched_barrier(0);
        LDB(Bf0, par, 0);
        MFMA16(0, AfA, Bf0, 0);
        asm volatile("s_waitcnt vmcnt(2)" ::: "memory");
        __builtin_amdgcn_s_barrier(); __builtin_amdgcn_sched_barrier(0);
        LDB(Bf1, par, 1);
        MFMA16(0, AfA, Bf1, 1);
        asm volatile("s_waitcnt vmcnt(0)" ::: "memory");
        __builtin_amdgcn_s_barrier(); __builtin_amdgcn_sched_barrier(0);
        LDA(AfB, par, 1);
        MFMA16(1, AfB, Bf1, 1);
        __builtin_amdgcn_s_barrier(); __builtin_amdgcn_sched_barrier(0);
        MFMA16(1, AfB, Bf0, 0);
    }

    // epilogue: C/D layout col=lane&15, row=(lane>>4)*4+r
    const float* bias = seg == 0 ? b0 : (seg == 1 ? b1 : b2);
    short* out = seg == 0 ? o0 : (seg == 1 ? o1 : o2);
    const float scl = (EPI == 0 && seg == 0) ? s0 : 1.f;
#pragma unroll
    for (int hm = 0; hm < 2; ++hm)
#pragma unroll
        for (int mi = 0; mi < 4; ++mi)
#pragma unroll
            for (int hn = 0; hn < 2; ++hn)
#pragma unroll
                for (int nj = 0; nj < 2; ++nj) {
                    int ncol = bnl * 256 + hn * 128 + wc * 32 + nj * 16 + (lane & 15);
                    float bv = bias[ncol];
#pragma unroll
                    for (int r = 0; r < 4; ++r) {
                        long grow = arow0 + hm * 128 + wr * 64 + mi * 16 +
                                    (lane >> 4) * 4 + r;
                        float v = acc[hm * 4 + mi][hn * 2 + nj][r] + bv;
                        if (EPI == 2) v = gelu_tanh(v);
                        else v *= scl;
                        out[grow * E_ + ncol] = f2bf(v);
                    }
                }
}

// ======================= R9-proven GEMM core (128x128, BK=64) ====================
#define GEMM_CORE(A_, W_, KDIM, ACC)                                                   \
    const int rsub = lane >> 3;                                                        \
    const int col  = (((lane & 7) ^ rsub) & 7) * 8;                                    \
    const int swz  = (lane & 7) << 3;                                                  \
    for (int kt = 0; kt < (KDIM); kt += 64) {                                          \
        __syncthreads();                                                               \
        _Pragma("unroll")                                                              \
        for (int i = 0; i < 4; ++i) {                                                  \
            int chunk = i * 4 + wave;                                                  \
            int row = chunk * 8 + rsub;                                                \
            const short* ga = (A_) + (arow0 + row) * (KDIM) + kt + col;                \
            const short* gb = (W_) + (brow0 + row) * (KDIM) + kt + col;                \
            __builtin_amdgcn_global_load_lds(                                          \
                (const __attribute__((address_space(1))) unsigned int*)ga,             \
                (__attribute__((address_space(3))) unsigned int*)&Als[chunk * 512],    \
                16, 0, 0);                                                             \
            __builtin_amdgcn_global_load_lds(                                          \
                (const __attribute__((address_space(1))) unsigned int*)gb,             \
                (__attribute__((address_space(3))) unsigned int*)&Bls[chunk * 512],    \
                16, 0, 0);                                                             \
        }                                                                              \
        __syncthreads();                                                               \
        _Pragma("unroll")                                                              \
        for (int kk = 0; kk < 2; ++kk) {                                               \
            bf16x8 af[4], bfr[4];                                                      \
            _Pragma("unroll")                                                          \
            for (int mi = 0; mi < 4; ++mi)                                             \
                af[mi] = *reinterpret_cast<const bf16x8*>(                             \
                    &Als[(((wm + mi * 16 + (lane & 15)) * 64 + kk * 32 +               \
                           (lane >> 4) * 8)) ^ swz]);                                  \
            _Pragma("unroll")                                                          \
            for (int nj = 0; nj < 4; ++nj)                                             \
                bfr[nj] = *reinterpret_cast<const bf16x8*>(                            \
                    &Bls[(((wn + nj * 16 + (lane & 15)) * 64 + kk * 32 +               \
                           (lane >> 4) * 8)) ^ swz]);                                  \
            _Pragma("unroll")                                                          \
            for (int mi = 0; mi < 4; ++mi)                                             \
                _Pragma("unroll")                                                      \
                for (int nj = 0; nj < 4; ++nj)                                         \
                    ACC[mi][nj] = __builtin_amdgcn_mfma_f32_16x16x32_bf16(             \
                        af[mi], bfr[nj], ACC[mi][nj], 0, 0, 0);                        \
        }                                                                              \
    }

// EPI: 0 = +bias -> bf16 ; 3 = +bias -> fp32
template<int EPI>
__global__ void gemm_bt(const short* __restrict__ A, const short* __restrict__ W,
                        const float* __restrict__ bias, void* __restrict__ Cout,
                        int K) {
    const int N = E_;
    const int NBN = E_ / 128;
    __shared__ short Als[128 * 64];
    __shared__ short Bls[128 * 64];
    const int tid  = threadIdx.x;
    const int wave = tid >> 6, lane = tid & 63;

    const int nwg = gridDim.x;
    const int qq = nwg >> 3, rr = nwg & 7;
    const int x = blockIdx.x & 7, ii = blockIdx.x >> 3;
    const int L = (x < rr ? x * (qq + 1) : rr * (qq + 1) + (x - rr) * qq) + ii;
    const int bm = L / NBN, bn = L % NBN;

    const int wm = (wave >> 1) * 64, wn = (wave & 1) * 64;
    f32x4 acc[4][4] = {};
    const long arow0 = (long)bm * 128;
    const long brow0 = (long)bn * 128;

    GEMM_CORE(A, W, K, acc)

#pragma unroll
    for (int mi = 0; mi < 4; ++mi) {
#pragma unroll
        for (int nj = 0; nj < 4; ++nj) {
            int gcol = bn * 128 + wn + nj * 16 + (lane & 15);
            float bv = bias[gcol];
#pragma unroll
            for (int r = 0; r < 4; ++r) {
                long grow = arow0 + wm + mi * 16 + (lane >> 4) * 4 + r;
                float v = acc[mi][nj][r] + bv;
                if (EPI == 3) ((float*)Cout)[grow * N + gcol] = v;
                else          ((short*)Cout)[grow * N + gcol] = f2bf(v);
            }
        }
    }
}

// ---------------- MFMA token mixer ----------------
template<int SIN, int KP, int PS, bool GELU, bool RESID>
__global__ void mixer_mfma(const short* __restrict__ IN, const short* __restrict__ Wp,
                           const float* __restrict__ bias, const short* __restrict__ Cat,
                           short* __restrict__ OUT) {
    __shared__ short lsT[64 * PS];
    const int e0 = blockIdx.x * 64;
    const int b  = blockIdx.y;
    const int tid = threadIdx.x, wave = tid >> 6, lane = tid & 63;

    const int eg = tid & 7;
    const int sl = tid >> 3;
    for (int sb = sl; sb < KP; sb += 32) {
        if (sb < SIN) {
            bf16x8 v = *reinterpret_cast<const bf16x8*>(
                &IN[((long)b * SIN + sb) * E_ + e0 + eg * 8]);
#pragma unroll
            for (int i = 0; i < 8; ++i)
                lsT[(eg * 8 + i) * PS + sb] = v[i];
        } else {
#pragma unroll
            for (int i = 0; i < 8; ++i)
                lsT[(eg * 8 + i) * PS + sb] = 0;
        }
    }
    __syncthreads();

    const int ebase = wave * 16;
    f32x4 acc[5] = {};
#pragma unroll
    for (int ks = 0; ks < KP / 32; ++ks) {
        bf16x8 bfr = *reinterpret_cast<const bf16x8*>(
            &lsT[(ebase + (lane & 15)) * PS + ks * 32 + (lane >> 4) * 8]);
#pragma unroll
        for (int mt = 0; mt < 5; ++mt) {
            bf16x8 af = *reinterpret_cast<const bf16x8*>(
                &Wp[(mt * 16 + (lane & 15)) * KP + ks * 32 + (lane >> 4) * 8]);
            acc[mt] = __builtin_amdgcn_mfma_f32_16x16x32_bf16(af, bfr, acc[mt], 0, 0, 0);
        }
    }

    const int e = e0 + ebase + (lane & 15);
#pragma unroll
    for (int mt = 0; mt < 5; ++mt) {
#pragma unroll
        for (int r = 0; r < 4; ++r) {
            int t = mt * 16 + (lane >> 4) * 4 + r;
            if (t < T_) {
                float v = acc[mt][r] + bias[t];
                if (GELU) v = gelu_tanh(v);
                if (RESID) v += bf2f(Cat[((long)b * T2_ + T_ + t) * E_ + e]);
                OUT[((long)b * T_ + t) * E_ + e] = f2bf(v);
            }
        }
    }
}

// ---------------- fused MFMA attention: one WAVE per (b,h), both passes ----------------
#define ASTR 104
__global__ __launch_bounds__(64, 1)
void attn_mfma(const short* __restrict__ Qm,
               const short* __restrict__ Km, const short* __restrict__ Vm,
               const short* __restrict__ KAm, const short* __restrict__ VAm,
               short* __restrict__ Cat) {
    __shared__ short pls[80 * ASTR];
    __shared__ short vt[64 * ASTR];
    const int hh = blockIdx.x;
    const int b = hh / H_, h = hh % H_;
    const int lane = threadIdx.x & 63;
    const int colbase = lane & 15, g = lane >> 4;
    const long base = ((long)b * T_) * E_ + h * 64;

    for (int pass = 0; pass < 2; ++pass) {
        const short* Kp = pass ? KAm : Km;
        const short* Vp = pass ? VAm : Vm;
        const bool causal = (pass == 0);
        const int rowoff = pass ? 0 : T_;

        {
            int4 z = {0, 0, 0, 0};
#pragma unroll
            for (int it = 0; it < 4; ++it) {
                int idx = it * 64 + lane;
                int row = idx >> 2, cb = idx & 3;
                *reinterpret_cast<int4*>(&vt[row * ASTR + 64 + cb * 8]) = z;
            }
#pragma unroll
            for (int it = 0; it < 3; ++it) {
                int idx = it * 64 + lane;
                if (idx < 160) {
                    int row = idx >> 1, cb = idx & 1;
                    *reinterpret_cast<int4*>(&pls[row * ASTR + 80 + cb * 8]) = z;
                }
            }
        }

        {
            const short* vb = Vp + base + (long)lane * E_;
#pragma unroll
            for (int dg = 0; dg < 8; ++dg) {
                bf16x8 v = *reinterpret_cast<const bf16x8*>(vb + dg * 8);
#pragma unroll
                for (int i = 0; i < 8; ++i) vt[(dg * 8 + i) * ASTR + lane] = v[i];
            }
            if (lane < T_ - 64) {
                const short* vb2 = Vp + base + (long)(64 + lane) * E_;
#pragma unroll
                for (int dg = 0; dg < 8; ++dg) {
                    bf16x8 v = *reinterpret_cast<const bf16x8*>(vb2 + dg * 8);
#pragma unroll
                    for (int i = 0; i < 8; ++i) vt[(dg * 8 + i) * ASTR + 64 + lane] = v[i];
                }
            }
        }

        f32x4 sacc[5][5] = {};
#pragma unroll
        for (int kk = 0; kk < 2; ++kk) {
            bf16x8 qf[5];
#pragma unroll
            for (int mi = 0; mi < 5; ++mi) {
                int t = mi * 16 + colbase; t = t > 76 ? 76 : t;
                qf[mi] = *reinterpret_cast<const bf16x8*>(
                    Qm + base + (long)t * E_ + kk * 32 + g * 8);
            }
#pragma unroll
            for (int nj = 0; nj < 5; ++nj) {
                int s = nj * 16 + colbase; s = s > 76 ? 76 : s;
                bf16x8 kf = *reinterpret_cast<const bf16x8*>(
                    Kp + base + (long)s * E_ + kk * 32 + g * 8);
#pragma unroll
                for (int mi = 0; mi < 5; ++mi)
                    sacc[mi][nj] = __builtin_amdgcn_mfma_f32_16x16x32_bf16(
                        qf[mi], kf, sacc[mi][nj], 0, 0, 0);
            }
        }

        float inv[5][4];
#pragma unroll
        for (int mi = 0; mi < 5; ++mi) {
#pragma unroll
            for (int r = 0; r < 4; ++r) {
                int t = mi * 16 + g * 4 + r;
                float mx = -3.0e38f;
#pragma unroll
                for (int nj = 0; nj < 5; ++nj) {
                    int s = nj * 16 + colbase;
                    bool ok = causal ? (s <= t) : (s < T_);
                    if (ok) mx = fmaxf(mx, sacc[mi][nj][r]);
                }
#pragma unroll
                for (int o = 1; o <= 8; o <<= 1) mx = fmaxf(mx, __shfl_xor(mx, o));
                float sum = 0.f;
#pragma unroll
                for (int nj = 0; nj < 5; ++nj) {
                    int s = nj * 16 + colbase;
                    bool ok = causal ? (s <= t) : (s < T_);
                    float pv = ok ? __expf(sacc[mi][nj][r] - mx) : 0.f;
                    sacc[mi][nj][r] = pv;
                    sum += pv;
                }
#pragma unroll
                for (int o = 1; o <= 8; o <<= 1) sum += __shfl_xor(sum, o);
                inv[mi][r] = 1.0f / sum;
            }
        }

#pragma unroll
        for (int mi = 0; mi < 5; ++mi)
#pragma unroll
            for (int nj = 0; nj < 5; ++nj)
#pragma unroll
                for (int r = 0; r < 4; ++r)
                    pls[(mi * 16 + g * 4 + r) * ASTR + nj * 16 + colbase] =
                        f2bf(sacc[mi][nj][r]);

        f32x4 cacc[5][4] = {};
#pragma unroll
        for (int ks = 0; ks < 3; ++ks) {
            bf16x8 pa[5];
#pragma unroll
            for (int mi = 0; mi < 5; ++mi)
                pa[mi] = *reinterpret_cast<const bf16x8*>(
                    &pls[(mi * 16 + colbase) * ASTR + ks * 32 + g * 8]);
#pragma unroll
            for (int nd = 0; nd < 4; ++nd) {
                bf16x8 vf = *reinterpret_cast<const bf16x8*>(
                    &vt[(nd * 16 + colbase) * ASTR + ks * 32 + g * 8]);
#pragma unroll
                for (int mi = 0; mi < 5; ++mi)
                    cacc[mi][nd] = __builtin_amdgcn_mfma_f32_16x16x32_bf16(
                        pa[mi], vf, cacc[mi][nd], 0, 0, 0);
            }
        }

#pragma unroll
        for (int mi = 0; mi < 5; ++mi)
#pragma unroll
            for (int nd = 0; nd < 4; ++nd)
#pragma unroll
                for (int r = 0; r < 4; ++r) {
                    int t = mi * 16 + g * 4 + r;
                    if (t < T_) {
                        float val = cacc[mi][nd][r] * inv[mi][r];
                        Cat[((long)b * T2_ + rowoff + t) * E_ + h * 64 + nd * 16 + colbase] =
                            f2bf(val);
                    }
                }
    }
}

extern "C" void kernel_launch(void* const* d_in, const int* in_sizes, int n_in,
                              void* d_out, int out_size, void* d_ws, size_t ws_size,
                              hipStream_t stream) {
    const float* hidden = (const float*)d_in[0];
    const float* embeds = (const float*)d_in[1];
    const float* q_w  = (const float*)d_in[3];  const float* q_b  = (const float*)d_in[4];
    const float* k_w  = (const float*)d_in[5];  const float* k_b  = (const float*)d_in[6];
    const float* v_w  = (const float*)d_in[7];  const float* v_b  = (const float*)d_in[8];
    const float* o_w  = (const float*)d_in[9];  const float* o_b  = (const float*)d_in[10];
    const float* ka_w = (const float*)d_in[11]; const float* ka_b = (const float*)d_in[12];
    const float* va_w = (const float*)d_in[13]; const float* va_b = (const float*)d_in[14];
    const float* zc1_w = (const float*)d_in[15]; const float* zc1_b = (const float*)d_in[16];
    const float* zt1_w = (const float*)d_in[17]; const float* zt1_b = (const float*)d_in[18];
    const float* zc2_w = (const float*)d_in[19]; const float* zc2_b = (const float*)d_in[20];
    const float* zt2_w = (const float*)d_in[21]; const float* zt2_b = (const float*)d_in[22];

    char* ws = (char*)d_ws;
    const size_t WSZ = (size_t)E_ * E_ * 2;
    const size_t ASZ = (size_t)MTOK * E_ * 2;
    short* Wq  = (short*)(ws + 0 * WSZ);         // Wq|Wk|Wv contiguous
    short* Wka = (short*)(ws + 3 * WSZ);         // Wka|Wva contiguous
    short* Wz1 = (short*)(ws + 5 * WSZ);
    short* Wz2 = (short*)(ws + 6 * WSZ);
    short* Wo  = (short*)(ws + 7 * WSZ);
    char* p = ws + 8 * WSZ;
    short* Ahs  = (short*)p; p += ASZ;
    short* Aemb = (short*)p; p += ASZ;
    short* Qb   = (short*)p; p += ASZ;
    short* Kb   = (short*)p; p += ASZ;
    short* Vb   = (short*)p; p += ASZ;
    short* KAb  = (short*)p; p += ASZ;
    short* VAb  = (short*)p; p += ASZ;
    short* Wz1p = (short*)p; p += 80 * 160 * 2;
    short* Wz2p = (short*)p; p += 80 * 96 * 2;
    short* CAT = Ahs;   // aliases, lifetimes disjoint
    short* Y   = KAb;
    short* X2  = Qb;
    short* X3  = Kb;
    short* S   = Vb;

    if (ws_size < (size_t)(p - ws)) return;

    cast_f32_bf16<<<2048, 256, 0, stream>>>(hidden, Ahs,  MTOK * E_ / 4);
    cast_f32_bf16<<<2048, 256, 0, stream>>>(embeds, Aemb, MTOK * E_ / 4);
    cast8_f32_bf16<<<2048, 256, 0, stream>>>(q_w, k_w, v_w, ka_w, va_w, zc1_w, zc2_w, o_w,
                                             Wq);
    pad_weight<<<(80 * 160 + 255) / 256, 256, 0, stream>>>(zt1_w, Wz1p, 77, 154, 160);
    pad_weight<<<(80 * 96 + 255) / 256, 256, 0, stream>>>(zt2_w, Wz2p, 77, 77, 96);

    const int gQKV  = (MTOK / 256) * (3 * E_ / 256);    // 77*15 = 1155
    const int gKAVA = (MTOK / 256) * (2 * E_ / 256);    // 77*10 = 770
    const int gZC1  = (MTOK2 / 256) * (E_ / 256);       // 154*5 = 770
    const int g154  = (MTOK / 128) * (E_ / 128);        // 1540
    // fused projections on the 4-phase reg-cached 256x256 kernel
    qgemm<3, 0><<<gQKV, 512, 0, stream>>>(Ahs, Wq, q_b, k_b, v_b,
                                          Qb, Kb, Vb, 0.125f);
    qgemm<2, 0><<<gKAVA, 512, 0, stream>>>(Aemb, Wka, ka_b, va_b, va_b,
                                           KAb, VAb, VAb, 1.f);
    attn_mfma<<<B_ * H_, 64, 0, stream>>>(Qb, Kb, Vb, KAb, VAb, CAT);
    // zipper: zc1 on the 4-phase kernel (gelu epilogue)
    qgemm<1, 2><<<gZC1, 512, 0, stream>>>(CAT, Wz1, zc1_b, zc1_b, zc1_b,
                                          Y, Y, Y, 1.f);
    mixer_mfma<154, 160, 168, true, false><<<dim3(E_ / 64, B_), 256, 0, stream>>>(
        Y, Wz1p, zt1_b, nullptr, X2);
    gemm_bt<0><<<g154, 256, 0, stream>>>(X2, Wz2, zc2_b, X3, E_);
    mixer_mfma<77, 96, 104, false, true><<<dim3(E_ / 64, B_), 256, 0, stream>>>(
        X3, Wz2p, zt2_b, CAT, S);
    gemm_bt<3><<<g154, 256, 0, stream>>>(S, Wo, o_b, (float*)d_out, E_);
}

// Round 15
// 1064.916 us; speedup vs baseline: 1.1440x; 1.1440x over previous
//
#include <hip/hip_runtime.h>
#include <stdint.h>

#define B_    256
#define T_    77
#define E_    1280
#define H_    20
#define T2_   154
#define MTOK  19712   // B_*T_
#define MTOK2 39424   // B_*T2_

typedef float f32x4 __attribute__((ext_vector_type(4)));
typedef short bf16x8 __attribute__((ext_vector_type(8)));

__device__ inline float bf2f(short s) {
    return __uint_as_float(((unsigned)(unsigned short)s) << 16);
}
__device__ inline short f2bf(float f) {
    unsigned u = __float_as_uint(f);
    u += 0x7fff + ((u >> 16) & 1);   // RNE
    return (short)(u >> 16);
}
__device__ inline float gelu_tanh(float x) {   // jax.nn.gelu approximate=True
    float x3 = x * x * x;
    return 0.5f * x * (1.0f + tanhf(0.7978845608028654f * (x + 0.044715f * x3)));
}

// ---------------- fp32 -> bf16 cast ----------------
__global__ void cast_f32_bf16(const float* __restrict__ in, short* __restrict__ out, int n4) {
    int i = blockIdx.x * blockDim.x + threadIdx.x;
    int stride = gridDim.x * blockDim.x;
    for (; i < n4; i += stride) {
        float4 v = reinterpret_cast<const float4*>(in)[i];
        short4 o;
        o.x = f2bf(v.x); o.y = f2bf(v.y); o.z = f2bf(v.z); o.w = f2bf(v.w);
        reinterpret_cast<short4*>(out)[i] = o;
    }
}

// ---------------- merged 8-weight cast: out regions contiguous in ws ----------------
__global__ void cast8_f32_bf16(const float* __restrict__ s0, const float* __restrict__ s1,
                               const float* __restrict__ s2, const float* __restrict__ s3,
                               const float* __restrict__ s4, const float* __restrict__ s5,
                               const float* __restrict__ s6, const float* __restrict__ s7,
                               short* __restrict__ out) {
    const int per = E_ * E_ / 4;    // 409600 float4 per weight
    int i = blockIdx.x * blockDim.x + threadIdx.x;
    int stride = gridDim.x * blockDim.x;
    for (; i < 8 * per; i += stride) {
        int w = i / per, j = i - w * per;
        const float* src = w == 0 ? s0 : w == 1 ? s1 : w == 2 ? s2 : w == 3 ? s3
                         : w == 4 ? s4 : w == 5 ? s5 : w == 6 ? s6 : s7;
        float4 v = reinterpret_cast<const float4*>(src)[j];
        short4 o;
        o.x = f2bf(v.x); o.y = f2bf(v.y); o.z = f2bf(v.z); o.w = f2bf(v.w);
        reinterpret_cast<short4*>(out)[i] = o;
    }
}

// ---------------- pad token-mix weight: fp32 (rows x cols) -> bf16 [80][KP], zero pad ----
__global__ void pad_weight(const float* __restrict__ W, short* __restrict__ Wp,
                           int rows, int cols, int KP) {
    int i = blockIdx.x * 256 + threadIdx.x;
    if (i >= 80 * KP) return;
    int t = i / KP, s = i - t * KP;
    Wp[i] = (t < rows && s < cols) ? f2bf(W[t * cols + s]) : (short)0;
}

// ======================= R9-proven GEMM core (128x128, BK=64) ====================
// 4 waves (each 64x64), global_load_lds w=16, T1 bijective XCD swizzle,
// T2 both-sides LDS XOR swizzle (R9: conflicts 4.7e7 -> 0). ~910 TF fused.
// R10/R13/R14 deep-pipeline variants all regressed (occupancy/lockstep) — this
// simple 2-barrier structure is the session-best GEMM.
#define GEMM_CORE(A_, W_, KDIM, ACC)                                                   \
    const int rsub = lane >> 3;                                                        \
    const int col  = (((lane & 7) ^ rsub) & 7) * 8;                                    \
    const int swz  = (lane & 7) << 3;                                                  \
    for (int kt = 0; kt < (KDIM); kt += 64) {                                          \
        __syncthreads();                                                               \
        _Pragma("unroll")                                                              \
        for (int i = 0; i < 4; ++i) {                                                  \
            int chunk = i * 4 + wave;                                                  \
            int row = chunk * 8 + rsub;                                                \
            const short* ga = (A_) + (arow0 + row) * (KDIM) + kt + col;                \
            const short* gb = (W_) + (brow0 + row) * (KDIM) + kt + col;                \
            __builtin_amdgcn_global_load_lds(                                          \
                (const __attribute__((address_space(1))) unsigned int*)ga,             \
                (__attribute__((address_space(3))) unsigned int*)&Als[chunk * 512],    \
                16, 0, 0);                                                             \
            __builtin_amdgcn_global_load_lds(                                          \
                (const __attribute__((address_space(1))) unsigned int*)gb,             \
                (__attribute__((address_space(3))) unsigned int*)&Bls[chunk * 512],    \
                16, 0, 0);                                                             \
        }                                                                              \
        __syncthreads();                                                               \
        _Pragma("unroll")                                                              \
        for (int kk = 0; kk < 2; ++kk) {                                               \
            bf16x8 af[4], bfr[4];                                                      \
            _Pragma("unroll")                                                          \
            for (int mi = 0; mi < 4; ++mi)                                             \
                af[mi] = *reinterpret_cast<const bf16x8*>(                             \
                    &Als[(((wm + mi * 16 + (lane & 15)) * 64 + kk * 32 +               \
                           (lane >> 4) * 8)) ^ swz]);                                  \
            _Pragma("unroll")                                                          \
            for (int nj = 0; nj < 4; ++nj)                                             \
                bfr[nj] = *reinterpret_cast<const bf16x8*>(                            \
                    &Bls[(((wn + nj * 16 + (lane & 15)) * 64 + kk * 32 +               \
                           (lane >> 4) * 8)) ^ swz]);                                  \
            _Pragma("unroll")                                                          \
            for (int mi = 0; mi < 4; ++mi)                                             \
                _Pragma("unroll")                                                      \
                for (int nj = 0; nj < 4; ++nj)                                         \
                    ACC[mi][nj] = __builtin_amdgcn_mfma_f32_16x16x32_bf16(             \
                        af[mi], bfr[nj], ACC[mi][nj], 0, 0, 0);                        \
        }                                                                              \
    }

// ---------------- generic GEMM: C[M,N=E] = A[M,K] @ W[N,K]^T (+epilogue) --------
// EPI: 0 = +bias -> bf16 ; 2 = gelu(+bias) -> bf16 ; 3 = +bias -> fp32
template<int EPI>
__global__ void gemm_bt(const short* __restrict__ A, const short* __restrict__ W,
                        const float* __restrict__ bias, void* __restrict__ Cout,
                        int K) {
    const int N = E_;
    const int NBN = E_ / 128;            // 10 N-tiles
    __shared__ short Als[128 * 64];
    __shared__ short Bls[128 * 64];
    const int tid  = threadIdx.x;
    const int wave = tid >> 6, lane = tid & 63;

    const int nwg = gridDim.x;
    const int qq = nwg >> 3, rr = nwg & 7;
    const int x = blockIdx.x & 7, ii = blockIdx.x >> 3;
    const int L = (x < rr ? x * (qq + 1) : rr * (qq + 1) + (x - rr) * qq) + ii;
    const int bm = L / NBN, bn = L % NBN;

    const int wm = (wave >> 1) * 64, wn = (wave & 1) * 64;
    f32x4 acc[4][4] = {};
    const long arow0 = (long)bm * 128;
    const long brow0 = (long)bn * 128;

    GEMM_CORE(A, W, K, acc)

#pragma unroll
    for (int mi = 0; mi < 4; ++mi) {
#pragma unroll
        for (int nj = 0; nj < 4; ++nj) {
            int gcol = bn * 128 + wn + nj * 16 + (lane & 15);
            float bv = bias[gcol];
#pragma unroll
            for (int r = 0; r < 4; ++r) {
                long grow = arow0 + wm + mi * 16 + (lane >> 4) * 4 + r;
                float v = acc[mi][nj][r] + bv;
                if (EPI == 2) v = gelu_tanh(v);
                if (EPI == 3) ((float*)Cout)[grow * N + gcol] = v;
                else          ((short*)Cout)[grow * N + gcol] = f2bf(v);
            }
        }
    }
}

// ---------------- fused projection GEMM, SEG-MAJOR ordering ----------------
// W is NSEG concatenated [E][E] weights. Seg outermost (L/1540) -> concurrent
// W working set = one seg = 3.3 MB < 4 MB per-XCD L2 (R12: FETCH 613->219 MB).
template<int NSEG>
__global__ void gemm_proj(const short* __restrict__ A, const short* __restrict__ W,
                          const float* __restrict__ b0, const float* __restrict__ b1,
                          const float* __restrict__ b2,
                          short* __restrict__ o0, short* __restrict__ o1,
                          short* __restrict__ o2, float s0) {
    const int PB = (MTOK / 128) * (E_ / 128);   // 1540 blocks per segment
    __shared__ short Als[128 * 64];
    __shared__ short Bls[128 * 64];
    const int tid  = threadIdx.x;
    const int wave = tid >> 6, lane = tid & 63;

    const int nwg = gridDim.x;
    const int qq = nwg >> 3, rr = nwg & 7;
    const int x = blockIdx.x & 7, ii = blockIdx.x >> 3;
    const int L = (x < rr ? x * (qq + 1) : rr * (qq + 1) + (x - rr) * qq) + ii;
    const int seg = L / PB;
    const int rem = L - seg * PB;
    const int bm = rem / (E_ / 128), bnl = rem % (E_ / 128);

    const int wm = (wave >> 1) * 64, wn = (wave & 1) * 64;
    f32x4 acc[4][4] = {};
    const long arow0 = (long)bm * 128;
    const long brow0 = (long)seg * E_ + bnl * 128;   // row into concatenated W
    const int K = E_;

    GEMM_CORE(A, W, K, acc)

    const float* bias = seg == 0 ? b0 : (seg == 1 ? b1 : b2);
    short* out = seg == 0 ? o0 : (seg == 1 ? o1 : o2);
    const float scl = seg == 0 ? s0 : 1.f;
#pragma unroll
    for (int mi = 0; mi < 4; ++mi) {
#pragma unroll
        for (int nj = 0; nj < 4; ++nj) {
            int gcol = bnl * 128 + wn + nj * 16 + (lane & 15);
            float bv = bias[gcol];
#pragma unroll
            for (int r = 0; r < 4; ++r) {
                long grow = arow0 + wm + mi * 16 + (lane >> 4) * 4 + r;
                out[grow * E_ + gcol] = f2bf((acc[mi][nj][r] + bv) * scl);
            }
        }
    }
}

// ---------------- MFMA token mixer ----------------
template<int SIN, int KP, int PS, bool GELU, bool RESID>
__global__ void mixer_mfma(const short* __restrict__ IN, const short* __restrict__ Wp,
                           const float* __restrict__ bias, const short* __restrict__ Cat,
                           short* __restrict__ OUT) {
    __shared__ short lsT[64 * PS];
    const int e0 = blockIdx.x * 64;
    const int b  = blockIdx.y;
    const int tid = threadIdx.x, wave = tid >> 6, lane = tid & 63;

    const int eg = tid & 7;
    const int sl = tid >> 3;
    for (int sb = sl; sb < KP; sb += 32) {
        if (sb < SIN) {
            bf16x8 v = *reinterpret_cast<const bf16x8*>(
                &IN[((long)b * SIN + sb) * E_ + e0 + eg * 8]);
#pragma unroll
            for (int i = 0; i < 8; ++i)
                lsT[(eg * 8 + i) * PS + sb] = v[i];
        } else {
#pragma unroll
            for (int i = 0; i < 8; ++i)
                lsT[(eg * 8 + i) * PS + sb] = 0;
        }
    }
    __syncthreads();

    const int ebase = wave * 16;
    f32x4 acc[5] = {};
#pragma unroll
    for (int ks = 0; ks < KP / 32; ++ks) {
        bf16x8 bfr = *reinterpret_cast<const bf16x8*>(
            &lsT[(ebase + (lane & 15)) * PS + ks * 32 + (lane >> 4) * 8]);
#pragma unroll
        for (int mt = 0; mt < 5; ++mt) {
            bf16x8 af = *reinterpret_cast<const bf16x8*>(
                &Wp[(mt * 16 + (lane & 15)) * KP + ks * 32 + (lane >> 4) * 8]);
            acc[mt] = __builtin_amdgcn_mfma_f32_16x16x32_bf16(af, bfr, acc[mt], 0, 0, 0);
        }
    }

    const int e = e0 + ebase + (lane & 15);
#pragma unroll
    for (int mt = 0; mt < 5; ++mt) {
#pragma unroll
        for (int r = 0; r < 4; ++r) {
            int t = mt * 16 + (lane >> 4) * 4 + r;
            if (t < T_) {
                float v = acc[mt][r] + bias[t];
                if (GELU) v = gelu_tanh(v);
                if (RESID) v += bf2f(Cat[((long)b * T2_ + T_ + t) * E_ + e]);
                OUT[((long)b * T_ + t) * E_ + e] = f2bf(v);
            }
        }
    }
}

// ---------------- fused MFMA attention: one WAVE per (b,h), both passes ----------------
#define ASTR 104   // LDS row stride (shorts): 16B-aligned, <=2-way banks on b128
__global__ __launch_bounds__(64, 1)
void attn_mfma(const short* __restrict__ Qm,
               const short* __restrict__ Km, const short* __restrict__ Vm,
               const short* __restrict__ KAm, const short* __restrict__ VAm,
               short* __restrict__ Cat) {
    __shared__ short pls[80 * ASTR];
    __shared__ short vt[64 * ASTR];
    const int hh = blockIdx.x;
    const int b = hh / H_, h = hh % H_;
    const int lane = threadIdx.x & 63;
    const int colbase = lane & 15, g = lane >> 4;
    const long base = ((long)b * T_) * E_ + h * 64;

    for (int pass = 0; pass < 2; ++pass) {
        const short* Kp = pass ? KAm : Km;
        const short* Vp = pass ? VAm : Vm;
        const bool causal = (pass == 0);
        const int rowoff = pass ? 0 : T_;

        {
            int4 z = {0, 0, 0, 0};
#pragma unroll
            for (int it = 0; it < 4; ++it) {
                int idx = it * 64 + lane;
                int row = idx >> 2, cb = idx & 3;
                *reinterpret_cast<int4*>(&vt[row * ASTR + 64 + cb * 8]) = z;
            }
#pragma unroll
            for (int it = 0; it < 3; ++it) {
                int idx = it * 64 + lane;
                if (idx < 160) {
                    int row = idx >> 1, cb = idx & 1;
                    *reinterpret_cast<int4*>(&pls[row * ASTR + 80 + cb * 8]) = z;
                }
            }
        }

        {
            const short* vb = Vp + base + (long)lane * E_;
#pragma unroll
            for (int dg = 0; dg < 8; ++dg) {
                bf16x8 v = *reinterpret_cast<const bf16x8*>(vb + dg * 8);
#pragma unroll
                for (int i = 0; i < 8; ++i) vt[(dg * 8 + i) * ASTR + lane] = v[i];
            }
            if (lane < T_ - 64) {
                const short* vb2 = Vp + base + (long)(64 + lane) * E_;
#pragma unroll
                for (int dg = 0; dg < 8; ++dg) {
                    bf16x8 v = *reinterpret_cast<const bf16x8*>(vb2 + dg * 8);
#pragma unroll
                    for (int i = 0; i < 8; ++i) vt[(dg * 8 + i) * ASTR + 64 + lane] = v[i];
                }
            }
        }

        f32x4 sacc[5][5] = {};
#pragma unroll
        for (int kk = 0; kk < 2; ++kk) {
            bf16x8 qf[5];
#pragma unroll
            for (int mi = 0; mi < 5; ++mi) {
                int t = mi * 16 + colbase; t = t > 76 ? 76 : t;
                qf[mi] = *reinterpret_cast<const bf16x8*>(
                    Qm + base + (long)t * E_ + kk * 32 + g * 8);
            }
#pragma unroll
            for (int nj = 0; nj < 5; ++nj) {
                int s = nj * 16 + colbase; s = s > 76 ? 76 : s;
                bf16x8 kf = *reinterpret_cast<const bf16x8*>(
                    Kp + base + (long)s * E_ + kk * 32 + g * 8);
#pragma unroll
                for (int mi = 0; mi < 5; ++mi)
                    sacc[mi][nj] = __builtin_amdgcn_mfma_f32_16x16x32_bf16(
                        qf[mi], kf, sacc[mi][nj], 0, 0, 0);
            }
        }

        float inv[5][4];
#pragma unroll
        for (int mi = 0; mi < 5; ++mi) {
#pragma unroll
            for (int r = 0; r < 4; ++r) {
                int t = mi * 16 + g * 4 + r;
                float mx = -3.0e38f;
#pragma unroll
                for (int nj = 0; nj < 5; ++nj) {
                    int s = nj * 16 + colbase;
                    bool ok = causal ? (s <= t) : (s < T_);
                    if (ok) mx = fmaxf(mx, sacc[mi][nj][r]);
                }
#pragma unroll
                for (int o = 1; o <= 8; o <<= 1) mx = fmaxf(mx, __shfl_xor(mx, o));
                float sum = 0.f;
#pragma unroll
                for (int nj = 0; nj < 5; ++nj) {
                    int s = nj * 16 + colbase;
                    bool ok = causal ? (s <= t) : (s < T_);
                    float pv = ok ? __expf(sacc[mi][nj][r] - mx) : 0.f;
                    sacc[mi][nj][r] = pv;
                    sum += pv;
                }
#pragma unroll
                for (int o = 1; o <= 8; o <<= 1) sum += __shfl_xor(sum, o);
                inv[mi][r] = 1.0f / sum;
            }
        }

#pragma unroll
        for (int mi = 0; mi < 5; ++mi)
#pragma unroll
            for (int nj = 0; nj < 5; ++nj)
#pragma unroll
                for (int r = 0; r < 4; ++r)
                    pls[(mi * 16 + g * 4 + r) * ASTR + nj * 16 + colbase] =
                        f2bf(sacc[mi][nj][r]);

        f32x4 cacc[5][4] = {};
#pragma unroll
        for (int ks = 0; ks < 3; ++ks) {
            bf16x8 pa[5];
#pragma unroll
            for (int mi = 0; mi < 5; ++mi)
                pa[mi] = *reinterpret_cast<const bf16x8*>(
                    &pls[(mi * 16 + colbase) * ASTR + ks * 32 + g * 8]);
#pragma unroll
            for (int nd = 0; nd < 4; ++nd) {
                bf16x8 vf = *reinterpret_cast<const bf16x8*>(
                    &vt[(nd * 16 + colbase) * ASTR + ks * 32 + g * 8]);
#pragma unroll
                for (int mi = 0; mi < 5; ++mi)
                    cacc[mi][nd] = __builtin_amdgcn_mfma_f32_16x16x32_bf16(
                        pa[mi], vf, cacc[mi][nd], 0, 0, 0);
            }
        }

#pragma unroll
        for (int mi = 0; mi < 5; ++mi)
#pragma unroll
            for (int nd = 0; nd < 4; ++nd)
#pragma unroll
                for (int r = 0; r < 4; ++r) {
                    int t = mi * 16 + g * 4 + r;
                    if (t < T_) {
                        float val = cacc[mi][nd][r] * inv[mi][r];
                        Cat[((long)b * T2_ + rowoff + t) * E_ + h * 64 + nd * 16 + colbase] =
                            f2bf(val);
                    }
                }
    }
}

extern "C" void kernel_launch(void* const* d_in, const int* in_sizes, int n_in,
                              void* d_out, int out_size, void* d_ws, size_t ws_size,
                              hipStream_t stream) {
    const float* hidden = (const float*)d_in[0];
    const float* embeds = (const float*)d_in[1];
    // d_in[2] causal_mask unused (exactly triu(-1e9) -> applied analytically)
    const float* q_w  = (const float*)d_in[3];  const float* q_b  = (const float*)d_in[4];
    const float* k_w  = (const float*)d_in[5];  const float* k_b  = (const float*)d_in[6];
    const float* v_w  = (const float*)d_in[7];  const float* v_b  = (const float*)d_in[8];
    const float* o_w  = (const float*)d_in[9];  const float* o_b  = (const float*)d_in[10];
    const float* ka_w = (const float*)d_in[11]; const float* ka_b = (const float*)d_in[12];
    const float* va_w = (const float*)d_in[13]; const float* va_b = (const float*)d_in[14];
    const float* zc1_w = (const float*)d_in[15]; const float* zc1_b = (const float*)d_in[16];
    const float* zt1_w = (const float*)d_in[17]; const float* zt1_b = (const float*)d_in[18];
    const float* zc2_w = (const float*)d_in[19]; const float* zc2_b = (const float*)d_in[20];
    const float* zt2_w = (const float*)d_in[21]; const float* zt2_b = (const float*)d_in[22];

    char* ws = (char*)d_ws;
    const size_t WSZ = (size_t)E_ * E_ * 2;      // 3,276,800 B per weight
    const size_t ASZ = (size_t)MTOK * E_ * 2;    // 50,462,720 B per activation
    short* Wq  = (short*)(ws + 0 * WSZ);         // Wq|Wk|Wv contiguous = [3840][1280]
    short* Wka = (short*)(ws + 3 * WSZ);         // Wka|Wva contiguous = [2560][1280]
    short* Wz1 = (short*)(ws + 5 * WSZ);
    short* Wz2 = (short*)(ws + 6 * WSZ);
    short* Wo  = (short*)(ws + 7 * WSZ);
    char* p = ws + 8 * WSZ;
    short* Ahs  = (short*)p; p += ASZ;
    short* Aemb = (short*)p; p += ASZ;
    short* Qb   = (short*)p; p += ASZ;
    short* Kb   = (short*)p; p += ASZ;
    short* Vb   = (short*)p; p += ASZ;
    short* KAb  = (short*)p; p += ASZ;
    short* VAb  = (short*)p; p += ASZ;
    short* Wz1p = (short*)p; p += 80 * 160 * 2;  // padded zt1_w bf16 [80][160]
    short* Wz2p = (short*)p; p += 80 * 96 * 2;   // padded zt2_w bf16 [80][96]
    // aliases (lifetimes disjoint in stream order):
    short* CAT = Ahs;   // (B,2T,E) over Ahs+Aemb   — written after projections
    short* Y   = KAb;   // (B,2T,E) over KAb+VAb    — written after attention
    short* X2  = Qb;
    short* X3  = Kb;
    short* S   = Vb;

    if (ws_size < (size_t)(p - ws)) return;   // clean-fail signal

    // casts (8 weights in one dispatch; out regions contiguous at ws+0..8*WSZ)
    cast_f32_bf16<<<2048, 256, 0, stream>>>(hidden, Ahs,  MTOK * E_ / 4);
    cast_f32_bf16<<<2048, 256, 0, stream>>>(embeds, Aemb, MTOK * E_ / 4);
    cast8_f32_bf16<<<2048, 256, 0, stream>>>(q_w, k_w, v_w, ka_w, va_w, zc1_w, zc2_w, o_w,
                                             Wq);
    pad_weight<<<(80 * 160 + 255) / 256, 256, 0, stream>>>(zt1_w, Wz1p, 77, 154, 160);
    pad_weight<<<(80 * 96 + 255) / 256, 256, 0, stream>>>(zt2_w, Wz2p, 77, 77, 96);

    const int gQKV  = (MTOK / 128) * (3 * E_ / 128);   // 154*30 = 4620
    const int gKAVA = (MTOK / 128) * (2 * E_ / 128);   // 154*20 = 3080
    const int g154  = (MTOK / 128) * (E_ / 128);       // 1540
    const int g308  = (MTOK2 / 128) * (E_ / 128);      // 3080
    // fused projections (seg-major): QKV from hidden (Q scaled), KA/VA from embeds
    gemm_proj<3><<<gQKV, 256, 0, stream>>>(Ahs, Wq, q_b, k_b, v_b,
                                           Qb, Kb, Vb, 0.125f);
    gemm_proj<2><<<gKAVA, 256, 0, stream>>>(Aemb, Wka, ka_b, va_b, nullptr,
                                            KAb, VAb, nullptr, 1.f);
    // fused attention (both passes): adapter rows [0,77), self rows [77,154) of CAT
    attn_mfma<<<B_ * H_, 64, 0, stream>>>(Qb, Kb, Vb, KAb, VAb, CAT);
    // zipper
    gemm_bt<2><<<g308, 256, 0, stream>>>(CAT, Wz1, zc1_b, Y, E_);      // gelu
    mixer_mfma<154, 160, 168, true, false><<<dim3(E_ / 64, B_), 256, 0, stream>>>(
        Y, Wz1p, zt1_b, nullptr, X2);
    gemm_bt<0><<<g154, 256, 0, stream>>>(X2, Wz2, zc2_b, X3, E_);
    mixer_mfma<77, 96, 104, false, true><<<dim3(E_ / 64, B_), 256, 0, stream>>>(
        X3, Wz2p, zt2_b, CAT, S);
    // output projection -> fp32 d_out
    gemm_bt<3><<<g154, 256, 0, stream>>>(S, Wo, o_b, (float*)d_out, E_);
}

// Round 16
// 1037.401 us; speedup vs baseline: 1.1744x; 1.0265x over previous
//
#include <hip/hip_runtime.h>
#include <stdint.h>

#define B_    256
#define T_    77
#define E_    1280
#define H_    20
#define T2_   154
#define MTOK  19712   // B_*T_
#define MTOK2 39424   // B_*T2_

typedef float f32x4 __attribute__((ext_vector_type(4)));
typedef short bf16x8 __attribute__((ext_vector_type(8)));

__device__ inline float bf2f(short s) {
    return __uint_as_float(((unsigned)(unsigned short)s) << 16);
}
__device__ inline short f2bf(float f) {
    unsigned u = __float_as_uint(f);
    u += 0x7fff + ((u >> 16) & 1);   // RNE
    return (short)(u >> 16);
}
__device__ inline float gelu_tanh(float x) {   // jax.nn.gelu approximate=True
    float x3 = x * x * x;
    return 0.5f * x * (1.0f + tanhf(0.7978845608028654f * (x + 0.044715f * x3)));
}

// ---------------- single prep kernel: both activation casts + 8-weight cast + pads ----
// Region map over flat item index (float4 units for casts, scalars for pads):
//   [0,N0)    hidden  -> Ahs      (float4 cast)
//   [N0,N1)   embeds  -> Aemb     (float4 cast)
//   [N1,N2)   8 weights -> Wq..   (float4 cast, contiguous out)
//   [N2,N3)   zt1 pad -> Wz1p     (scalar, [80][160], zero pad)
//   [N3,N4)   zt2 pad -> Wz2p     (scalar, [80][96], zero pad)
__global__ void prep_all(const float* __restrict__ hidden, const float* __restrict__ embeds,
                         const float* __restrict__ q_w,  const float* __restrict__ k_w,
                         const float* __restrict__ v_w,  const float* __restrict__ ka_w,
                         const float* __restrict__ va_w, const float* __restrict__ zc1_w,
                         const float* __restrict__ zc2_w, const float* __restrict__ o_w,
                         const float* __restrict__ zt1_w, const float* __restrict__ zt2_w,
                         short* __restrict__ Ahs, short* __restrict__ Aemb,
                         short* __restrict__ Wq8, short* __restrict__ Wz1p,
                         short* __restrict__ Wz2p) {
    const int NA  = MTOK * E_ / 4;        // 6,307,840
    const int PER = E_ * E_ / 4;          // 409,600
    const int N0 = NA, N1 = 2 * NA, N2 = N1 + 8 * PER;
    const int N3 = N2 + 80 * 160, N4 = N3 + 80 * 96;
    int i = blockIdx.x * blockDim.x + threadIdx.x;
    int stride = gridDim.x * blockDim.x;
    for (; i < N4; i += stride) {
        if (i < N1) {                      // activation casts
            const float* src = i < N0 ? hidden : embeds;
            short* dst = i < N0 ? Ahs : Aemb;
            int j = i < N0 ? i : i - N0;
            float4 v = reinterpret_cast<const float4*>(src)[j];
            short4 o;
            o.x = f2bf(v.x); o.y = f2bf(v.y); o.z = f2bf(v.z); o.w = f2bf(v.w);
            reinterpret_cast<short4*>(dst)[j] = o;
        } else if (i < N2) {               // 8-weight cast, contiguous out
            int j = i - N1;
            int w = j / PER, jj = j - w * PER;
            const float* src = w == 0 ? q_w : w == 1 ? k_w : w == 2 ? v_w : w == 3 ? ka_w
                             : w == 4 ? va_w : w == 5 ? zc1_w : w == 6 ? zc2_w : o_w;
            float4 v = reinterpret_cast<const float4*>(src)[jj];
            short4 o;
            o.x = f2bf(v.x); o.y = f2bf(v.y); o.z = f2bf(v.z); o.w = f2bf(v.w);
            reinterpret_cast<short4*>(Wq8)[j] = o;
        } else if (i < N3) {               // zt1 pad: [80][160] from [77][154]
            int j = i - N2;
            int t = j / 160, s = j - t * 160;
            Wz1p[j] = (t < 77 && s < 154) ? f2bf(zt1_w[t * 154 + s]) : (short)0;
        } else {                           // zt2 pad: [80][96] from [77][77]
            int j = i - N3;
            int t = j / 96, s = j - t * 96;
            Wz2p[j] = (t < 77 && s < 77) ? f2bf(zt2_w[t * 77 + s]) : (short)0;
        }
    }
}

// ======================= R9-proven GEMM core (128x128, BK=64) ====================
// 4 waves (each 64x64), global_load_lds w=16, T1 bijective XCD swizzle,
// T2 both-sides LDS XOR swizzle (R9: conflicts 4.7e7 -> 0). ~910 TF fused.
// R10/R13/R14 deep-pipeline variants all regressed (occupancy/lockstep) — this
// simple 2-barrier structure is the session-best GEMM.
#define GEMM_CORE(A_, W_, KDIM, ACC)                                                   \
    const int rsub = lane >> 3;                                                        \
    const int col  = (((lane & 7) ^ rsub) & 7) * 8;                                    \
    const int swz  = (lane & 7) << 3;                                                  \
    for (int kt = 0; kt < (KDIM); kt += 64) {                                          \
        __syncthreads();                                                               \
        _Pragma("unroll")                                                              \
        for (int i = 0; i < 4; ++i) {                                                  \
            int chunk = i * 4 + wave;                                                  \
            int row = chunk * 8 + rsub;                                                \
            const short* ga = (A_) + (arow0 + row) * (KDIM) + kt + col;                \
            const short* gb = (W_) + (brow0 + row) * (KDIM) + kt + col;                \
            __builtin_amdgcn_global_load_lds(                                          \
                (const __attribute__((address_space(1))) unsigned int*)ga,             \
                (__attribute__((address_space(3))) unsigned int*)&Als[chunk * 512],    \
                16, 0, 0);                                                             \
            __builtin_amdgcn_global_load_lds(                                          \
                (const __attribute__((address_space(1))) unsigned int*)gb,             \
                (__attribute__((address_space(3))) unsigned int*)&Bls[chunk * 512],    \
                16, 0, 0);                                                             \
        }                                                                              \
        __syncthreads();                                                               \
        _Pragma("unroll")                                                              \
        for (int kk = 0; kk < 2; ++kk) {                                               \
            bf16x8 af[4], bfr[4];                                                      \
            _Pragma("unroll")                                                          \
            for (int mi = 0; mi < 4; ++mi)                                             \
                af[mi] = *reinterpret_cast<const bf16x8*>(                             \
                    &Als[(((wm + mi * 16 + (lane & 15)) * 64 + kk * 32 +               \
                           (lane >> 4) * 8)) ^ swz]);                                  \
            _Pragma("unroll")                                                          \
            for (int nj = 0; nj < 4; ++nj)                                             \
                bfr[nj] = *reinterpret_cast<const bf16x8*>(                            \
                    &Bls[(((wn + nj * 16 + (lane & 15)) * 64 + kk * 32 +               \
                           (lane >> 4) * 8)) ^ swz]);                                  \
            _Pragma("unroll")                                                          \
            for (int mi = 0; mi < 4; ++mi)                                             \
                _Pragma("unroll")                                                      \
                for (int nj = 0; nj < 4; ++nj)                                         \
                    ACC[mi][nj] = __builtin_amdgcn_mfma_f32_16x16x32_bf16(             \
                        af[mi], bfr[nj], ACC[mi][nj], 0, 0, 0);                        \
        }                                                                              \
    }

// ---------------- generic GEMM: C[M,N=E] = A[M,K] @ W[N,K]^T (+epilogue) --------
// EPI: 0 = +bias -> bf16 ; 2 = gelu(+bias) -> bf16 ; 3 = +bias -> fp32
template<int EPI>
__global__ void gemm_bt(const short* __restrict__ A, const short* __restrict__ W,
                        const float* __restrict__ bias, void* __restrict__ Cout,
                        int K) {
    const int N = E_;
    const int NBN = E_ / 128;            // 10 N-tiles
    __shared__ short Als[128 * 64];
    __shared__ short Bls[128 * 64];
    const int tid  = threadIdx.x;
    const int wave = tid >> 6, lane = tid & 63;

    const int nwg = gridDim.x;
    const int qq = nwg >> 3, rr = nwg & 7;
    const int x = blockIdx.x & 7, ii = blockIdx.x >> 3;
    const int L = (x < rr ? x * (qq + 1) : rr * (qq + 1) + (x - rr) * qq) + ii;
    const int bm = L / NBN, bn = L % NBN;

    const int wm = (wave >> 1) * 64, wn = (wave & 1) * 64;
    f32x4 acc[4][4] = {};
    const long arow0 = (long)bm * 128;
    const long brow0 = (long)bn * 128;

    GEMM_CORE(A, W, K, acc)

#pragma unroll
    for (int mi = 0; mi < 4; ++mi) {
#pragma unroll
        for (int nj = 0; nj < 4; ++nj) {
            int gcol = bn * 128 + wn + nj * 16 + (lane & 15);
            float bv = bias[gcol];
#pragma unroll
            for (int r = 0; r < 4; ++r) {
                long grow = arow0 + wm + mi * 16 + (lane >> 4) * 4 + r;
                float v = acc[mi][nj][r] + bv;
                if (EPI == 2) v = gelu_tanh(v);
                if (EPI == 3) ((float*)Cout)[grow * N + gcol] = v;
                else          ((short*)Cout)[grow * N + gcol] = f2bf(v);
            }
        }
    }
}

// ---------------- fused projection GEMM, SEG-MAJOR ordering ----------------
// W is NSEG concatenated [E][E] weights. Seg outermost (L/1540) -> concurrent
// W working set = one seg = 3.3 MB < 4 MB per-XCD L2 (R12: FETCH 613->219 MB).
template<int NSEG>
__global__ void gemm_proj(const short* __restrict__ A, const short* __restrict__ W,
                          const float* __restrict__ b0, const float* __restrict__ b1,
                          const float* __restrict__ b2,
                          short* __restrict__ o0, short* __restrict__ o1,
                          short* __restrict__ o2, float s0) {
    const int PB = (MTOK / 128) * (E_ / 128);   // 1540 blocks per segment
    __shared__ short Als[128 * 64];
    __shared__ short Bls[128 * 64];
    const int tid  = threadIdx.x;
    const int wave = tid >> 6, lane = tid & 63;

    const int nwg = gridDim.x;
    const int qq = nwg >> 3, rr = nwg & 7;
    const int x = blockIdx.x & 7, ii = blockIdx.x >> 3;
    const int L = (x < rr ? x * (qq + 1) : rr * (qq + 1) + (x - rr) * qq) + ii;
    const int seg = L / PB;
    const int rem = L - seg * PB;
    const int bm = rem / (E_ / 128), bnl = rem % (E_ / 128);

    const int wm = (wave >> 1) * 64, wn = (wave & 1) * 64;
    f32x4 acc[4][4] = {};
    const long arow0 = (long)bm * 128;
    const long brow0 = (long)seg * E_ + bnl * 128;   // row into concatenated W
    const int K = E_;

    GEMM_CORE(A, W, K, acc)

    const float* bias = seg == 0 ? b0 : (seg == 1 ? b1 : b2);
    short* out = seg == 0 ? o0 : (seg == 1 ? o1 : o2);
    const float scl = seg == 0 ? s0 : 1.f;
#pragma unroll
    for (int mi = 0; mi < 4; ++mi) {
#pragma unroll
        for (int nj = 0; nj < 4; ++nj) {
            int gcol = bnl * 128 + wn + nj * 16 + (lane & 15);
            float bv = bias[gcol];
#pragma unroll
            for (int r = 0; r < 4; ++r) {
                long grow = arow0 + wm + mi * 16 + (lane >> 4) * 4 + r;
                out[grow * E_ + gcol] = f2bf((acc[mi][nj][r] + bv) * scl);
            }
        }
    }
}

// ---------------- MFMA token mixer ----------------
template<int SIN, int KP, int PS, bool GELU, bool RESID>
__global__ void mixer_mfma(const short* __restrict__ IN, const short* __restrict__ Wp,
                           const float* __restrict__ bias, const short* __restrict__ Cat,
                           short* __restrict__ OUT) {
    __shared__ short lsT[64 * PS];
    const int e0 = blockIdx.x * 64;
    const int b  = blockIdx.y;
    const int tid = threadIdx.x, wave = tid >> 6, lane = tid & 63;

    const int eg = tid & 7;
    const int sl = tid >> 3;
    for (int sb = sl; sb < KP; sb += 32) {
        if (sb < SIN) {
            bf16x8 v = *reinterpret_cast<const bf16x8*>(
                &IN[((long)b * SIN + sb) * E_ + e0 + eg * 8]);
#pragma unroll
            for (int i = 0; i < 8; ++i)
                lsT[(eg * 8 + i) * PS + sb] = v[i];
        } else {
#pragma unroll
            for (int i = 0; i < 8; ++i)
                lsT[(eg * 8 + i) * PS + sb] = 0;
        }
    }
    __syncthreads();

    const int ebase = wave * 16;
    f32x4 acc[5] = {};
#pragma unroll
    for (int ks = 0; ks < KP / 32; ++ks) {
        bf16x8 bfr = *reinterpret_cast<const bf16x8*>(
            &lsT[(ebase + (lane & 15)) * PS + ks * 32 + (lane >> 4) * 8]);
#pragma unroll
        for (int mt = 0; mt < 5; ++mt) {
            bf16x8 af = *reinterpret_cast<const bf16x8*>(
                &Wp[(mt * 16 + (lane & 15)) * KP + ks * 32 + (lane >> 4) * 8]);
            acc[mt] = __builtin_amdgcn_mfma_f32_16x16x32_bf16(af, bfr, acc[mt], 0, 0, 0);
        }
    }

    const int e = e0 + ebase + (lane & 15);
#pragma unroll
    for (int mt = 0; mt < 5; ++mt) {
#pragma unroll
        for (int r = 0; r < 4; ++r) {
            int t = mt * 16 + (lane >> 4) * 4 + r;
            if (t < T_) {
                float v = acc[mt][r] + bias[t];
                if (GELU) v = gelu_tanh(v);
                if (RESID) v += bf2f(Cat[((long)b * T2_ + T_ + t) * E_ + e]);
                OUT[((long)b * T_ + t) * E_ + e] = f2bf(v);
            }
        }
    }
}

// ---------------- fused MFMA attention: one WAVE per (b,h,pass) ----------------
// R16: the two passes (self-causal / adapter) are split across gridDim.y=2 —
// half the serial work per block, 2x blocks for cross-block latency overlap at
// the same 5-blocks/CU LDS occupancy.
#define ASTR 104   // LDS row stride (shorts): 16B-aligned, <=2-way banks on b128
__global__ __launch_bounds__(64, 1)
void attn_mfma(const short* __restrict__ Qm,
               const short* __restrict__ Km, const short* __restrict__ Vm,
               const short* __restrict__ KAm, const short* __restrict__ VAm,
               short* __restrict__ Cat) {
    __shared__ short pls[80 * ASTR];
    __shared__ short vt[64 * ASTR];
    const int hh = blockIdx.x;
    const int pass = blockIdx.y;
    const int b = hh / H_, h = hh % H_;
    const int lane = threadIdx.x & 63;
    const int colbase = lane & 15, g = lane >> 4;
    const long base = ((long)b * T_) * E_ + h * 64;

    const short* Kp = pass ? KAm : Km;
    const short* Vp = pass ? VAm : Vm;
    const bool causal = (pass == 0);
    const int rowoff = pass ? 0 : T_;

    // ---- zero LDS K-tails (cols >= valid range) BEFORE staging ----
    {
        int4 z = {0, 0, 0, 0};
#pragma unroll
        for (int it = 0; it < 4; ++it) {          // vt rows 0..63, cols 64..95
            int idx = it * 64 + lane;
            int row = idx >> 2, cb = idx & 3;
            *reinterpret_cast<int4*>(&vt[row * ASTR + 64 + cb * 8]) = z;
        }
#pragma unroll
        for (int it = 0; it < 3; ++it) {          // pls rows 0..79, cols 80..95
            int idx = it * 64 + lane;
            if (idx < 160) {
                int row = idx >> 1, cb = idx & 1;
                *reinterpret_cast<int4*>(&pls[row * ASTR + 80 + cb * 8]) = z;
            }
        }
    }

    // ---- stage V^T: vt[d][s] = V[s][d]; lane = s (transpose writes conflict-free) ----
    {
        const short* vb = Vp + base + (long)lane * E_;
#pragma unroll
        for (int dg = 0; dg < 8; ++dg) {
            bf16x8 v = *reinterpret_cast<const bf16x8*>(vb + dg * 8);
#pragma unroll
            for (int i = 0; i < 8; ++i) vt[(dg * 8 + i) * ASTR + lane] = v[i];
        }
        if (lane < T_ - 64) {
            const short* vb2 = Vp + base + (long)(64 + lane) * E_;
#pragma unroll
            for (int dg = 0; dg < 8; ++dg) {
                bf16x8 v = *reinterpret_cast<const bf16x8*>(vb2 + dg * 8);
#pragma unroll
                for (int i = 0; i < 8; ++i) vt[(dg * 8 + i) * ASTR + 64 + lane] = v[i];
            }
        }
    }

    // ---- S = Q.K^T (frags from global; rows clamped to 76) ----
    f32x4 sacc[5][5] = {};
#pragma unroll
    for (int kk = 0; kk < 2; ++kk) {
        bf16x8 qf[5];
#pragma unroll
        for (int mi = 0; mi < 5; ++mi) {
            int t = mi * 16 + colbase; t = t > 76 ? 76 : t;
            qf[mi] = *reinterpret_cast<const bf16x8*>(
                Qm + base + (long)t * E_ + kk * 32 + g * 8);
        }
#pragma unroll
        for (int nj = 0; nj < 5; ++nj) {
            int s = nj * 16 + colbase; s = s > 76 ? 76 : s;
            bf16x8 kf = *reinterpret_cast<const bf16x8*>(
                Kp + base + (long)s * E_ + kk * 32 + g * 8);
#pragma unroll
            for (int mi = 0; mi < 5; ++mi)
                sacc[mi][nj] = __builtin_amdgcn_mfma_f32_16x16x32_bf16(
                    qf[mi], kf, sacc[mi][nj], 0, 0, 0);
        }
    }

    // ---- masked softmax in C-layout; row-reduce across the 16-lane group ----
    float inv[5][4];
#pragma unroll
    for (int mi = 0; mi < 5; ++mi) {
#pragma unroll
        for (int r = 0; r < 4; ++r) {
            int t = mi * 16 + g * 4 + r;
            float mx = -3.0e38f;
#pragma unroll
            for (int nj = 0; nj < 5; ++nj) {
                int s = nj * 16 + colbase;
                bool ok = causal ? (s <= t) : (s < T_);
                if (ok) mx = fmaxf(mx, sacc[mi][nj][r]);
            }
#pragma unroll
            for (int o = 1; o <= 8; o <<= 1) mx = fmaxf(mx, __shfl_xor(mx, o));
            float sum = 0.f;
#pragma unroll
            for (int nj = 0; nj < 5; ++nj) {
                int s = nj * 16 + colbase;
                bool ok = causal ? (s <= t) : (s < T_);
                float pv = ok ? __expf(sacc[mi][nj][r] - mx) : 0.f;
                sacc[mi][nj][r] = pv;
                sum += pv;
            }
#pragma unroll
            for (int o = 1; o <= 8; o <<= 1) sum += __shfl_xor(sum, o);
            inv[mi][r] = 1.0f / sum;
        }
    }

    // ---- write unnormalized P (bf16) to LDS ----
#pragma unroll
    for (int mi = 0; mi < 5; ++mi)
#pragma unroll
        for (int nj = 0; nj < 5; ++nj)
#pragma unroll
            for (int r = 0; r < 4; ++r)
                pls[(mi * 16 + g * 4 + r) * ASTR + nj * 16 + colbase] =
                    f2bf(sacc[mi][nj][r]);

    // ---- ctx = P.V via mfma (A = P rows, B = V^T rows; K = 96) ----
    f32x4 cacc[5][4] = {};
#pragma unroll
    for (int ks = 0; ks < 3; ++ks) {
        bf16x8 pa[5];
#pragma unroll
        for (int mi = 0; mi < 5; ++mi)
            pa[mi] = *reinterpret_cast<const bf16x8*>(
                &pls[(mi * 16 + colbase) * ASTR + ks * 32 + g * 8]);
#pragma unroll
        for (int nd = 0; nd < 4; ++nd) {
            bf16x8 vf = *reinterpret_cast<const bf16x8*>(
                &vt[(nd * 16 + colbase) * ASTR + ks * 32 + g * 8]);
#pragma unroll
            for (int mi = 0; mi < 5; ++mi)
                cacc[mi][nd] = __builtin_amdgcn_mfma_f32_16x16x32_bf16(
                    pa[mi], vf, cacc[mi][nd], 0, 0, 0);
        }
    }

    // ---- epilogue: normalize by 1/rowsum, write CAT ----
#pragma unroll
    for (int mi = 0; mi < 5; ++mi)
#pragma unroll
        for (int nd = 0; nd < 4; ++nd)
#pragma unroll
            for (int r = 0; r < 4; ++r) {
                int t = mi * 16 + g * 4 + r;
                if (t < T_) {
                    float val = cacc[mi][nd][r] * inv[mi][r];
                    Cat[((long)b * T2_ + rowoff + t) * E_ + h * 64 + nd * 16 + colbase] =
                        f2bf(val);
                }
            }
}

extern "C" void kernel_launch(void* const* d_in, const int* in_sizes, int n_in,
                              void* d_out, int out_size, void* d_ws, size_t ws_size,
                              hipStream_t stream) {
    const float* hidden = (const float*)d_in[0];
    const float* embeds = (const float*)d_in[1];
    // d_in[2] causal_mask unused (exactly triu(-1e9) -> applied analytically)
    const float* q_w  = (const float*)d_in[3];  const float* q_b  = (const float*)d_in[4];
    const float* k_w  = (const float*)d_in[5];  const float* k_b  = (const float*)d_in[6];
    const float* v_w  = (const float*)d_in[7];  const float* v_b  = (const float*)d_in[8];
    const float* o_w  = (const float*)d_in[9];  const float* o_b  = (const float*)d_in[10];
    const float* ka_w = (const float*)d_in[11]; const float* ka_b = (const float*)d_in[12];
    const float* va_w = (const float*)d_in[13]; const float* va_b = (const float*)d_in[14];
    const float* zc1_w = (const float*)d_in[15]; const float* zc1_b = (const float*)d_in[16];
    const float* zt1_w = (const float*)d_in[17]; const float* zt1_b = (const float*)d_in[18];
    const float* zc2_w = (const float*)d_in[19]; const float* zc2_b = (const float*)d_in[20];
    const float* zt2_w = (const float*)d_in[21]; const float* zt2_b = (const float*)d_in[22];

    char* ws = (char*)d_ws;
    const size_t WSZ = (size_t)E_ * E_ * 2;      // 3,276,800 B per weight
    const size_t ASZ = (size_t)MTOK * E_ * 2;    // 50,462,720 B per activation
    short* Wq  = (short*)(ws + 0 * WSZ);         // Wq|Wk|Wv contiguous = [3840][1280]
    short* Wka = (short*)(ws + 3 * WSZ);         // Wka|Wva contiguous = [2560][1280]
    short* Wz1 = (short*)(ws + 5 * WSZ);
    short* Wz2 = (short*)(ws + 6 * WSZ);
    short* Wo  = (short*)(ws + 7 * WSZ);
    char* p = ws + 8 * WSZ;
    short* Ahs  = (short*)p; p += ASZ;
    short* Aemb = (short*)p; p += ASZ;
    short* Qb   = (short*)p; p += ASZ;
    short* Kb   = (short*)p; p += ASZ;
    short* Vb   = (short*)p; p += ASZ;
    short* KAb  = (short*)p; p += ASZ;
    short* VAb  = (short*)p; p += ASZ;
    short* Wz1p = (short*)p; p += 80 * 160 * 2;  // padded zt1_w bf16 [80][160]
    short* Wz2p = (short*)p; p += 80 * 96 * 2;   // padded zt2_w bf16 [80][96]
    // aliases (lifetimes disjoint in stream order):
    short* CAT = Ahs;   // (B,2T,E) over Ahs+Aemb   — written after projections
    short* Y   = KAb;   // (B,2T,E) over KAb+VAb    — written after attention
    short* X2  = Qb;
    short* X3  = Kb;
    short* S   = Vb;

    if (ws_size < (size_t)(p - ws)) return;   // clean-fail signal

    // single prep dispatch: both activation casts + 8-weight cast + pads
    prep_all<<<4096, 256, 0, stream>>>(hidden, embeds, q_w, k_w, v_w, ka_w, va_w,
                                       zc1_w, zc2_w, o_w, zt1_w, zt2_w,
                                       Ahs, Aemb, Wq, Wz1p, Wz2p);

    const int gQKV  = (MTOK / 128) * (3 * E_ / 128);   // 154*30 = 4620
    const int gKAVA = (MTOK / 128) * (2 * E_ / 128);   // 154*20 = 3080
    const int g154  = (MTOK / 128) * (E_ / 128);       // 1540
    const int g308  = (MTOK2 / 128) * (E_ / 128);      // 3080
    // fused projections (seg-major): QKV from hidden (Q scaled), KA/VA from embeds
    gemm_proj<3><<<gQKV, 256, 0, stream>>>(Ahs, Wq, q_b, k_b, v_b,
                                           Qb, Kb, Vb, 0.125f);
    gemm_proj<2><<<gKAVA, 256, 0, stream>>>(Aemb, Wka, ka_b, va_b, nullptr,
                                            KAb, VAb, nullptr, 1.f);
    // fused attention, passes split over gridDim.y: y=0 self-causal -> rows [77,154),
    // y=1 adapter -> rows [0,77)
    attn_mfma<<<dim3(B_ * H_, 2), 64, 0, stream>>>(Qb, Kb, Vb, KAb, VAb, CAT);
    // zipper
    gemm_bt<2><<<g308, 256, 0, stream>>>(CAT, Wz1, zc1_b, Y, E_);      // gelu
    mixer_mfma<154, 160, 168, true, false><<<dim3(E_ / 64, B_), 256, 0, stream>>>(
        Y, Wz1p, zt1_b, nullptr, X2);
    gemm_bt<0><<<g154, 256, 0, stream>>>(X2, Wz2, zc2_b, X3, E_);
    mixer_mfma<77, 96, 104, false, true><<<dim3(E_ / 64, B_), 256, 0, stream>>>(
        X3, Wz2p, zt2_b, CAT, S);
    // output projection -> fp32 d_out
    gemm_bt<3><<<g154, 256, 0, stream>>>(S, Wo, o_b, (float*)d_out, E_);
}

// Round 17
// 1004.728 us; speedup vs baseline: 1.2125x; 1.0325x over previous
//
#include <hip/hip_runtime.h>
#include <stdint.h>

#define B_    256
#define T_    77
#define E_    1280
#define H_    20
#define T2_   154
#define MTOK  19712   // B_*T_
#define MTOK2 39424   // B_*T2_

typedef float f32x4 __attribute__((ext_vector_type(4)));
typedef short bf16x8 __attribute__((ext_vector_type(8)));

__device__ inline float bf2f(short s) {
    return __uint_as_float(((unsigned)(unsigned short)s) << 16);
}
__device__ inline short f2bf(float f) {
    unsigned u = __float_as_uint(f);
    u += 0x7fff + ((u >> 16) & 1);   // RNE
    return (short)(u >> 16);
}
__device__ inline float gelu_tanh(float x) {   // jax.nn.gelu approximate=True
    float x3 = x * x * x;
    return 0.5f * x * (1.0f + tanhf(0.7978845608028654f * (x + 0.044715f * x3)));
}

// ---------------- single prep kernel: both activation casts + 8-weight cast + pads ----
__global__ void prep_all(const float* __restrict__ hidden, const float* __restrict__ embeds,
                         const float* __restrict__ q_w,  const float* __restrict__ k_w,
                         const float* __restrict__ v_w,  const float* __restrict__ ka_w,
                         const float* __restrict__ va_w, const float* __restrict__ zc1_w,
                         const float* __restrict__ zc2_w, const float* __restrict__ o_w,
                         const float* __restrict__ zt1_w, const float* __restrict__ zt2_w,
                         short* __restrict__ Ahs, short* __restrict__ Aemb,
                         short* __restrict__ Wq8, short* __restrict__ Wz1p,
                         short* __restrict__ Wz2p) {
    const int NA  = MTOK * E_ / 4;        // 6,307,840
    const int PER = E_ * E_ / 4;          // 409,600
    const int N0 = NA, N1 = 2 * NA, N2 = N1 + 8 * PER;
    const int N3 = N2 + 80 * 160, N4 = N3 + 80 * 96;
    int i = blockIdx.x * blockDim.x + threadIdx.x;
    int stride = gridDim.x * blockDim.x;
    for (; i < N4; i += stride) {
        if (i < N1) {                      // activation casts
            const float* src = i < N0 ? hidden : embeds;
            short* dst = i < N0 ? Ahs : Aemb;
            int j = i < N0 ? i : i - N0;
            float4 v = reinterpret_cast<const float4*>(src)[j];
            short4 o;
            o.x = f2bf(v.x); o.y = f2bf(v.y); o.z = f2bf(v.z); o.w = f2bf(v.w);
            reinterpret_cast<short4*>(dst)[j] = o;
        } else if (i < N2) {               // 8-weight cast, contiguous out
            int j = i - N1;
            int w = j / PER, jj = j - w * PER;
            const float* src = w == 0 ? q_w : w == 1 ? k_w : w == 2 ? v_w : w == 3 ? ka_w
                             : w == 4 ? va_w : w == 5 ? zc1_w : w == 6 ? zc2_w : o_w;
            float4 v = reinterpret_cast<const float4*>(src)[jj];
            short4 o;
            o.x = f2bf(v.x); o.y = f2bf(v.y); o.z = f2bf(v.z); o.w = f2bf(v.w);
            reinterpret_cast<short4*>(Wq8)[j] = o;
        } else if (i < N3) {               // zt1 pad: [80][160] from [77][154]
            int j = i - N2;
            int t = j / 160, s = j - t * 160;
            Wz1p[j] = (t < 77 && s < 154) ? f2bf(zt1_w[t * 154 + s]) : (short)0;
        } else {                           // zt2 pad: [80][96] from [77][77]
            int j = i - N3;
            int t = j / 96, s = j - t * 96;
            Wz2p[j] = (t < 77 && s < 77) ? f2bf(zt2_w[t * 77 + s]) : (short)0;
        }
    }
}

// ======================= R9-proven GEMM core (128x128, BK=64) ====================
// 4 waves (each 64x64), global_load_lds w=16, T1 bijective XCD swizzle,
// T2 both-sides LDS XOR swizzle (R9: conflicts 4.7e7 -> 0). ~910 TF fused.
#define GEMM_CORE(A_, W_, KDIM, ACC)                                                   \
    const int rsub = lane >> 3;                                                        \
    const int col  = (((lane & 7) ^ rsub) & 7) * 8;                                    \
    const int swz  = (lane & 7) << 3;                                                  \
    for (int kt = 0; kt < (KDIM); kt += 64) {                                          \
        __syncthreads();                                                               \
        _Pragma("unroll")                                                              \
        for (int i = 0; i < 4; ++i) {                                                  \
            int chunk = i * 4 + wave;                                                  \
            int row = chunk * 8 + rsub;                                                \
            const short* ga = (A_) + (arow0 + row) * (KDIM) + kt + col;                \
            const short* gb = (W_) + (brow0 + row) * (KDIM) + kt + col;                \
            __builtin_amdgcn_global_load_lds(                                          \
                (const __attribute__((address_space(1))) unsigned int*)ga,             \
                (__attribute__((address_space(3))) unsigned int*)&Als[chunk * 512],    \
                16, 0, 0);                                                             \
            __builtin_amdgcn_global_load_lds(                                          \
                (const __attribute__((address_space(1))) unsigned int*)gb,             \
                (__attribute__((address_space(3))) unsigned int*)&Bls[chunk * 512],    \
                16, 0, 0);                                                             \
        }                                                                              \
        __syncthreads();                                                               \
        _Pragma("unroll")                                                              \
        for (int kk = 0; kk < 2; ++kk) {                                               \
            bf16x8 af[4], bfr[4];                                                      \
            _Pragma("unroll")                                                          \
            for (int mi = 0; mi < 4; ++mi)                                             \
                af[mi] = *reinterpret_cast<const bf16x8*>(                             \
                    &Als[(((wm + mi * 16 + (lane & 15)) * 64 + kk * 32 +               \
                           (lane >> 4) * 8)) ^ swz]);                                  \
            _Pragma("unroll")                                                          \
            for (int nj = 0; nj < 4; ++nj)                                             \
                bfr[nj] = *reinterpret_cast<const bf16x8*>(                            \
                    &Bls[(((wn + nj * 16 + (lane & 15)) * 64 + kk * 32 +               \
                           (lane >> 4) * 8)) ^ swz]);                                  \
            _Pragma("unroll")                                                          \
            for (int mi = 0; mi < 4; ++mi)                                             \
                _Pragma("unroll")                                                      \
                for (int nj = 0; nj < 4; ++nj)                                         \
                    ACC[mi][nj] = __builtin_amdgcn_mfma_f32_16x16x32_bf16(             \
                        af[mi], bfr[nj], ACC[mi][nj], 0, 0, 0);                        \
        }                                                                              \
    }

// ---------------- generic GEMM: C[M,N=E] = A[M,K] @ W[N,K]^T (+epilogue) --------
// EPI: 0 = +bias -> bf16 ; 2 = gelu(+bias) -> bf16 ; 3 = +bias -> fp32
template<int EPI>
__global__ void gemm_bt(const short* __restrict__ A, const short* __restrict__ W,
                        const float* __restrict__ bias, void* __restrict__ Cout,
                        int K) {
    const int N = E_;
    const int NBN = E_ / 128;            // 10 N-tiles
    __shared__ short Als[128 * 64];
    __shared__ short Bls[128 * 64];
    const int tid  = threadIdx.x;
    const int wave = tid >> 6, lane = tid & 63;

    const int nwg = gridDim.x;
    const int qq = nwg >> 3, rr = nwg & 7;
    const int x = blockIdx.x & 7, ii = blockIdx.x >> 3;
    const int L = (x < rr ? x * (qq + 1) : rr * (qq + 1) + (x - rr) * qq) + ii;
    const int bm = L / NBN, bn = L % NBN;

    const int wm = (wave >> 1) * 64, wn = (wave & 1) * 64;
    f32x4 acc[4][4] = {};
    const long arow0 = (long)bm * 128;
    const long brow0 = (long)bn * 128;

    GEMM_CORE(A, W, K, acc)

#pragma unroll
    for (int mi = 0; mi < 4; ++mi) {
#pragma unroll
        for (int nj = 0; nj < 4; ++nj) {
            int gcol = bn * 128 + wn + nj * 16 + (lane & 15);
            float bv = bias[gcol];
#pragma unroll
            for (int r = 0; r < 4; ++r) {
                long grow = arow0 + wm + mi * 16 + (lane >> 4) * 4 + r;
                float v = acc[mi][nj][r] + bv;
                if (EPI == 2) v = gelu_tanh(v);
                if (EPI == 3) ((float*)Cout)[grow * N + gcol] = v;
                else          ((short*)Cout)[grow * N + gcol] = f2bf(v);
            }
        }
    }
}

// ---------------- fused 5-seg projection GEMM, SEG-MAJOR ordering ----------------
// W = Wq|Wk|Wv|Wka|Wva contiguous ([6400][1280]). Segs 0-2 read Ahs (q,k,v),
// segs 3-4 read Aemb (ka,va); all selects wave-uniform. Seg outermost ->
// concurrent per-XCD W working set = 3.3 MB < 4 MB L2 (R12 invariant).
// One dispatch = one ramp-down tail instead of two (R17 merge).
__global__ void gemm_proj5(const short* __restrict__ Ahs, const short* __restrict__ Aemb,
                           const short* __restrict__ W,
                           const float* __restrict__ bq, const float* __restrict__ bk,
                           const float* __restrict__ bv, const float* __restrict__ bka,
                           const float* __restrict__ bva,
                           short* __restrict__ oq, short* __restrict__ ok,
                           short* __restrict__ ov, short* __restrict__ oka,
                           short* __restrict__ ova, float s0) {
    const int PB = (MTOK / 128) * (E_ / 128);   // 1540 blocks per segment
    __shared__ short Als[128 * 64];
    __shared__ short Bls[128 * 64];
    const int tid  = threadIdx.x;
    const int wave = tid >> 6, lane = tid & 63;

    const int nwg = gridDim.x;
    const int qq = nwg >> 3, rr = nwg & 7;
    const int x = blockIdx.x & 7, ii = blockIdx.x >> 3;
    const int L = (x < rr ? x * (qq + 1) : rr * (qq + 1) + (x - rr) * qq) + ii;
    const int seg = L / PB;
    const int rem = L - seg * PB;
    const int bm = rem / (E_ / 128), bnl = rem % (E_ / 128);

    const short* A = seg < 3 ? Ahs : Aemb;
    const int wm = (wave >> 1) * 64, wn = (wave & 1) * 64;
    f32x4 acc[4][4] = {};
    const long arow0 = (long)bm * 128;
    const long brow0 = (long)seg * E_ + bnl * 128;   // row into concatenated W
    const int K = E_;

    GEMM_CORE(A, W, K, acc)

    const float* bias = seg == 0 ? bq : seg == 1 ? bk : seg == 2 ? bv
                      : seg == 3 ? bka : bva;
    short* out = seg == 0 ? oq : seg == 1 ? ok : seg == 2 ? ov
               : seg == 3 ? oka : ova;
    const float scl = seg == 0 ? s0 : 1.f;
#pragma unroll
    for (int mi = 0; mi < 4; ++mi) {
#pragma unroll
        for (int nj = 0; nj < 4; ++nj) {
            int gcol = bnl * 128 + wn + nj * 16 + (lane & 15);
            float bv_ = bias[gcol];
#pragma unroll
            for (int r = 0; r < 4; ++r) {
                long grow = arow0 + wm + mi * 16 + (lane >> 4) * 4 + r;
                out[grow * E_ + gcol] = f2bf((acc[mi][nj][r] + bv_) * scl);
            }
        }
    }
}

// ---------------- MFMA token mixer ----------------
template<int SIN, int KP, int PS, bool GELU, bool RESID>
__global__ void mixer_mfma(const short* __restrict__ IN, const short* __restrict__ Wp,
                           const float* __restrict__ bias, const short* __restrict__ Cat,
                           short* __restrict__ OUT) {
    __shared__ short lsT[64 * PS];
    const int e0 = blockIdx.x * 64;
    const int b  = blockIdx.y;
    const int tid = threadIdx.x, wave = tid >> 6, lane = tid & 63;

    const int eg = tid & 7;
    const int sl = tid >> 3;
    for (int sb = sl; sb < KP; sb += 32) {
        if (sb < SIN) {
            bf16x8 v = *reinterpret_cast<const bf16x8*>(
                &IN[((long)b * SIN + sb) * E_ + e0 + eg * 8]);
#pragma unroll
            for (int i = 0; i < 8; ++i)
                lsT[(eg * 8 + i) * PS + sb] = v[i];
        } else {
#pragma unroll
            for (int i = 0; i < 8; ++i)
                lsT[(eg * 8 + i) * PS + sb] = 0;
        }
    }
    __syncthreads();

    const int ebase = wave * 16;
    f32x4 acc[5] = {};
#pragma unroll
    for (int ks = 0; ks < KP / 32; ++ks) {
        bf16x8 bfr = *reinterpret_cast<const bf16x8*>(
            &lsT[(ebase + (lane & 15)) * PS + ks * 32 + (lane >> 4) * 8]);
#pragma unroll
        for (int mt = 0; mt < 5; ++mt) {
            bf16x8 af = *reinterpret_cast<const bf16x8*>(
                &Wp[(mt * 16 + (lane & 15)) * KP + ks * 32 + (lane >> 4) * 8]);
            acc[mt] = __builtin_amdgcn_mfma_f32_16x16x32_bf16(af, bfr, acc[mt], 0, 0, 0);
        }
    }

    const int e = e0 + ebase + (lane & 15);
#pragma unroll
    for (int mt = 0; mt < 5; ++mt) {
#pragma unroll
        for (int r = 0; r < 4; ++r) {
            int t = mt * 16 + (lane >> 4) * 4 + r;
            if (t < T_) {
                float v = acc[mt][r] + bias[t];
                if (GELU) v = gelu_tanh(v);
                if (RESID) v += bf2f(Cat[((long)b * T2_ + T_ + t) * E_ + e]);
                OUT[((long)b * T_ + t) * E_ + e] = f2bf(v);
            }
        }
    }
}

// ---------------- fused MFMA attention: one WAVE per (b,h,pass) ----------------
#define ASTR 104   // LDS row stride (shorts): 16B-aligned, <=2-way banks on b128
__global__ __launch_bounds__(64, 1)
void attn_mfma(const short* __restrict__ Qm,
               const short* __restrict__ Km, const short* __restrict__ Vm,
               const short* __restrict__ KAm, const short* __restrict__ VAm,
               short* __restrict__ Cat) {
    __shared__ short pls[80 * ASTR];
    __shared__ short vt[64 * ASTR];
    const int hh = blockIdx.x;
    const int pass = blockIdx.y;
    const int b = hh / H_, h = hh % H_;
    const int lane = threadIdx.x & 63;
    const int colbase = lane & 15, g = lane >> 4;
    const long base = ((long)b * T_) * E_ + h * 64;

    const short* Kp = pass ? KAm : Km;
    const short* Vp = pass ? VAm : Vm;
    const bool causal = (pass == 0);
    const int rowoff = pass ? 0 : T_;

    {
        int4 z = {0, 0, 0, 0};
#pragma unroll
        for (int it = 0; it < 4; ++it) {          // vt rows 0..63, cols 64..95
            int idx = it * 64 + lane;
            int row = idx >> 2, cb = idx & 3;
            *reinterpret_cast<int4*>(&vt[row * ASTR + 64 + cb * 8]) = z;
        }
#pragma unroll
        for (int it = 0; it < 3; ++it) {          // pls rows 0..79, cols 80..95
            int idx = it * 64 + lane;
            if (idx < 160) {
                int row = idx >> 1, cb = idx & 1;
                *reinterpret_cast<int4*>(&pls[row * ASTR + 80 + cb * 8]) = z;
            }
        }
    }

    {
        const short* vb = Vp + base + (long)lane * E_;
#pragma unroll
        for (int dg = 0; dg < 8; ++dg) {
            bf16x8 v = *reinterpret_cast<const bf16x8*>(vb + dg * 8);
#pragma unroll
            for (int i = 0; i < 8; ++i) vt[(dg * 8 + i) * ASTR + lane] = v[i];
        }
        if (lane < T_ - 64) {
            const short* vb2 = Vp + base + (long)(64 + lane) * E_;
#pragma unroll
            for (int dg = 0; dg < 8; ++dg) {
                bf16x8 v = *reinterpret_cast<const bf16x8*>(vb2 + dg * 8);
#pragma unroll
                for (int i = 0; i < 8; ++i) vt[(dg * 8 + i) * ASTR + 64 + lane] = v[i];
            }
        }
    }

    f32x4 sacc[5][5] = {};
#pragma unroll
    for (int kk = 0; kk < 2; ++kk) {
        bf16x8 qf[5];
#pragma unroll
        for (int mi = 0; mi < 5; ++mi) {
            int t = mi * 16 + colbase; t = t > 76 ? 76 : t;
            qf[mi] = *reinterpret_cast<const bf16x8*>(
                Qm + base + (long)t * E_ + kk * 32 + g * 8);
        }
#pragma unroll
        for (int nj = 0; nj < 5; ++nj) {
            int s = nj * 16 + colbase; s = s > 76 ? 76 : s;
            bf16x8 kf = *reinterpret_cast<const bf16x8*>(
                Kp + base + (long)s * E_ + kk * 32 + g * 8);
#pragma unroll
            for (int mi = 0; mi < 5; ++mi)
                sacc[mi][nj] = __builtin_amdgcn_mfma_f32_16x16x32_bf16(
                    qf[mi], kf, sacc[mi][nj], 0, 0, 0);
        }
    }

    float inv[5][4];
#pragma unroll
    for (int mi = 0; mi < 5; ++mi) {
#pragma unroll
        for (int r = 0; r < 4; ++r) {
            int t = mi * 16 + g * 4 + r;
            float mx = -3.0e38f;
#pragma unroll
            for (int nj = 0; nj < 5; ++nj) {
                int s = nj * 16 + colbase;
                bool ok = causal ? (s <= t) : (s < T_);
                if (ok) mx = fmaxf(mx, sacc[mi][nj][r]);
            }
#pragma unroll
            for (int o = 1; o <= 8; o <<= 1) mx = fmaxf(mx, __shfl_xor(mx, o));
            float sum = 0.f;
#pragma unroll
            for (int nj = 0; nj < 5; ++nj) {
                int s = nj * 16 + colbase;
                bool ok = causal ? (s <= t) : (s < T_);
                float pv = ok ? __expf(sacc[mi][nj][r] - mx) : 0.f;
                sacc[mi][nj][r] = pv;
                sum += pv;
            }
#pragma unroll
            for (int o = 1; o <= 8; o <<= 1) sum += __shfl_xor(sum, o);
            inv[mi][r] = 1.0f / sum;
        }
    }

#pragma unroll
    for (int mi = 0; mi < 5; ++mi)
#pragma unroll
        for (int nj = 0; nj < 5; ++nj)
#pragma unroll
            for (int r = 0; r < 4; ++r)
                pls[(mi * 16 + g * 4 + r) * ASTR + nj * 16 + colbase] =
                    f2bf(sacc[mi][nj][r]);

    f32x4 cacc[5][4] = {};
#pragma unroll
    for (int ks = 0; ks < 3; ++ks) {
        bf16x8 pa[5];
#pragma unroll
        for (int mi = 0; mi < 5; ++mi)
            pa[mi] = *reinterpret_cast<const bf16x8*>(
                &pls[(mi * 16 + colbase) * ASTR + ks * 32 + g * 8]);
#pragma unroll
        for (int nd = 0; nd < 4; ++nd) {
            bf16x8 vf = *reinterpret_cast<const bf16x8*>(
                &vt[(nd * 16 + colbase) * ASTR + ks * 32 + g * 8]);
#pragma unroll
            for (int mi = 0; mi < 5; ++mi)
                cacc[mi][nd] = __builtin_amdgcn_mfma_f32_16x16x32_bf16(
                    pa[mi], vf, cacc[mi][nd], 0, 0, 0);
        }
    }

#pragma unroll
    for (int mi = 0; mi < 5; ++mi)
#pragma unroll
        for (int nd = 0; nd < 4; ++nd)
#pragma unroll
            for (int r = 0; r < 4; ++r) {
                int t = mi * 16 + g * 4 + r;
                if (t < T_) {
                    float val = cacc[mi][nd][r] * inv[mi][r];
                    Cat[((long)b * T2_ + rowoff + t) * E_ + h * 64 + nd * 16 + colbase] =
                        f2bf(val);
                }
            }
}

extern "C" void kernel_launch(void* const* d_in, const int* in_sizes, int n_in,
                              void* d_out, int out_size, void* d_ws, size_t ws_size,
                              hipStream_t stream) {
    const float* hidden = (const float*)d_in[0];
    const float* embeds = (const float*)d_in[1];
    // d_in[2] causal_mask unused (exactly triu(-1e9) -> applied analytically)
    const float* q_w  = (const float*)d_in[3];  const float* q_b  = (const float*)d_in[4];
    const float* k_w  = (const float*)d_in[5];  const float* k_b  = (const float*)d_in[6];
    const float* v_w  = (const float*)d_in[7];  const float* v_b  = (const float*)d_in[8];
    const float* o_w  = (const float*)d_in[9];  const float* o_b  = (const float*)d_in[10];
    const float* ka_w = (const float*)d_in[11]; const float* ka_b = (const float*)d_in[12];
    const float* va_w = (const float*)d_in[13]; const float* va_b = (const float*)d_in[14];
    const float* zc1_w = (const float*)d_in[15]; const float* zc1_b = (const float*)d_in[16];
    const float* zt1_w = (const float*)d_in[17]; const float* zt1_b = (const float*)d_in[18];
    const float* zc2_w = (const float*)d_in[19]; const float* zc2_b = (const float*)d_in[20];
    const float* zt2_w = (const float*)d_in[21]; const float* zt2_b = (const float*)d_in[22];

    char* ws = (char*)d_ws;
    const size_t WSZ = (size_t)E_ * E_ * 2;      // 3,276,800 B per weight
    const size_t ASZ = (size_t)MTOK * E_ * 2;    // 50,462,720 B per activation
    short* Wq  = (short*)(ws + 0 * WSZ);         // Wq|Wk|Wv|Wka|Wva contiguous = [6400][1280]
    short* Wz1 = (short*)(ws + 5 * WSZ);
    short* Wz2 = (short*)(ws + 6 * WSZ);
    short* Wo  = (short*)(ws + 7 * WSZ);
    char* p = ws + 8 * WSZ;
    short* Ahs  = (short*)p; p += ASZ;
    short* Aemb = (short*)p; p += ASZ;
    short* Qb   = (short*)p; p += ASZ;
    short* Kb   = (short*)p; p += ASZ;
    short* Vb   = (short*)p; p += ASZ;
    short* KAb  = (short*)p; p += ASZ;
    short* VAb  = (short*)p; p += ASZ;
    short* Wz1p = (short*)p; p += 80 * 160 * 2;  // padded zt1_w bf16 [80][160]
    short* Wz2p = (short*)p; p += 80 * 96 * 2;   // padded zt2_w bf16 [80][96]
    // aliases (lifetimes disjoint in stream order):
    short* CAT = Ahs;   // (B,2T,E) over Ahs+Aemb   — written after projections
    short* Y   = KAb;   // (B,2T,E) over KAb+VAb    — written after attention
    short* X2  = Qb;
    short* X3  = Kb;
    short* S   = Vb;

    if (ws_size < (size_t)(p - ws)) return;   // clean-fail signal

    // single prep dispatch: both activation casts + 8-weight cast + pads
    prep_all<<<4096, 256, 0, stream>>>(hidden, embeds, q_w, k_w, v_w, ka_w, va_w,
                                       zc1_w, zc2_w, o_w, zt1_w, zt2_w,
                                       Ahs, Aemb, Wq, Wz1p, Wz2p);

    const int gP5  = (MTOK / 128) * (5 * E_ / 128);   // 154*50 = 7700
    const int g154 = (MTOK / 128) * (E_ / 128);       // 1540
    const int g308 = (MTOK2 / 128) * (E_ / 128);      // 3080
    // all 5 projections in ONE seg-major dispatch (q,k,v from hidden; ka,va from embeds)
    gemm_proj5<<<gP5, 256, 0, stream>>>(Ahs, Aemb, Wq,
                                        q_b, k_b, v_b, ka_b, va_b,
                                        Qb, Kb, Vb, KAb, VAb, 0.125f);
    // fused attention, passes split over gridDim.y: y=0 self-causal -> rows [77,154),
    // y=1 adapter -> rows [0,77)
    attn_mfma<<<dim3(B_ * H_, 2), 64, 0, stream>>>(Qb, Kb, Vb, KAb, VAb, CAT);
    // zipper
    gemm_bt<2><<<g308, 256, 0, stream>>>(CAT, Wz1, zc1_b, Y, E_);      // gelu
    mixer_mfma<154, 160, 168, true, false><<<dim3(E_ / 64, B_), 256, 0, stream>>>(
        Y, Wz1p, zt1_b, nullptr, X2);
    gemm_bt<0><<<g154, 256, 0, stream>>>(X2, Wz2, zc2_b, X3, E_);
    mixer_mfma<77, 96, 104, false, true><<<dim3(E_ / 64, B_), 256, 0, stream>>>(
        X3, Wz2p, zt2_b, CAT, S);
    // output projection -> fp32 d_out
    gemm_bt<3><<<g154, 256, 0, stream>>>(S, Wo, o_b, (float*)d_out, E_);
}